// Round 9
// baseline (329.549 us; speedup 1.0000x reference)
//
#include <hip/hip_runtime.h>

// Problem constants (match reference)
#define N_NODES 40000
#define ISIZE   64
#define KNN     24
#define NE      (N_NODES * KNN)      // 960000 edges (= E_ADJ as well)
#define OMEGA   0.9f
#define CAP     64                   // per-node bucket capacity (max deg ~46)
#define NBUCK   80                   // buckets of 512 nodes (idx>>9)
#define LBUCK   10                   // buckets per XCD (NBUCK/8)
#define BCAP    16384                // adj edges per bucket capacity (mean 12288)
#define JBCAP   16384                // learner edges per bucket capacity
#define EPT     8                    // edges per thread in k_bin
#define PBCH    512                  // edges per block in k_scatter2

// ---- bf16 helpers (storage-only precision; all math in fp32) -------------
__device__ __forceinline__ float bf2f(unsigned short s) {
    return __uint_as_float(((unsigned)s) << 16);
}
__device__ __forceinline__ unsigned short f2bf(float f) {  // round-nearest-even
    unsigned u = __float_as_uint(f);
    u += 0x7fffu + ((u >> 16) & 1u);
    return (unsigned short)(u >> 16);
}
__device__ __forceinline__ float bflo(unsigned u) { return __uint_as_float(u << 16); }
__device__ __forceinline__ float bfhi(unsigned u) { return __uint_as_float(u & 0xffff0000u); }
__device__ __forceinline__ unsigned pack2(float lo, float hi) {
    return (unsigned)f2bf(lo) | ((unsigned)f2bf(hi) << 16);
}

// ---- bin BOTH edge sets: adj by col (pack r<<16|c), learner by j (pack (j&511)<<20|e)
__global__ void k_bin(const int* __restrict__ row, const int* __restrict__ col,
                      const int* __restrict__ j_idx,
                      int* __restrict__ bcnt, unsigned* __restrict__ bbuf,
                      unsigned* __restrict__ ovf2, int* __restrict__ ovf2_cnt,
                      int* __restrict__ jbcnt, unsigned* __restrict__ jbbuf,
                      unsigned* __restrict__ jovf, int* __restrict__ jovf_cnt) {
    __shared__ int lcnt[NBUCK];
    __shared__ int lbase[NBUCK];
    const int NB_ADJ = (NE + 256 * EPT - 1) / (256 * EPT);
    int tid = threadIdx.x;
    bool adj = (int)blockIdx.x < NB_ADJ;
    int blk = adj ? blockIdx.x : blockIdx.x - NB_ADJ;
    for (int b = tid; b < NBUCK; b += 256) lcnt[b] = 0;
    __syncthreads();
    int e0 = blk * (256 * EPT);
    int myslot[EPT]; int myb[EPT]; unsigned myp[EPT];
    for (int k = 0; k < EPT; k++) {
        int e = e0 + k * 256 + tid;
        if (e < NE) {
            int b; unsigned p;
            if (adj) { int r = row[e], c = col[e]; b = c >> 9; p = ((unsigned)r << 16) | (unsigned)c; }
            else     { int j = j_idx[e];           b = j >> 9; p = ((unsigned)(j & 511) << 20) | (unsigned)e; }
            myb[k] = b; myp[k] = p;
            myslot[k] = atomicAdd(&lcnt[b], 1);
        } else myb[k] = -1;
    }
    __syncthreads();
    int* gcnt = adj ? bcnt : jbcnt;
    for (int b = tid; b < NBUCK; b += 256)
        lbase[b] = (lcnt[b] > 0) ? atomicAdd(&gcnt[b], lcnt[b]) : 0;
    __syncthreads();
    unsigned* gbuf = adj ? bbuf : jbbuf;
    unsigned* govf = adj ? ovf2 : jovf;
    int* gocnt = adj ? ovf2_cnt : jovf_cnt;
    int capb = adj ? BCAP : JBCAP;
    for (int k = 0; k < EPT; k++) {
        if (myb[k] < 0) continue;
        int pos = lbase[myb[k]] + myslot[k];
        if (pos < capb) gbuf[myb[k] * capb + pos] = myp[k];
        else { int p = atomicAdd(gocnt, 1); govf[p] = myp[k]; }
    }
}

// ---- XCD-affine scatter into ebuf (+ adj-bin-overflow tail blocks) -------
__global__ void k_scatter2(const unsigned* __restrict__ bbuf, const int* __restrict__ bcnt,
                           int* __restrict__ cnt, unsigned short* __restrict__ ebuf,
                           unsigned* __restrict__ ovf, int* __restrict__ ovf_cnt,
                           const unsigned* __restrict__ ovf2, const int* __restrict__ ovf2_cnt) {
    const int MAIN = 8 * LBUCK * (BCAP / PBCH);   // 2560
    if ((int)blockIdx.x >= MAIN) {                // adj bin-overflow fallback (normally 0)
        int m = ovf2_cnt[0];
        for (int t = (blockIdx.x - MAIN) * 256 + threadIdx.x; t < m; t += 8 * 256) {
            unsigned p = ovf2[t];
            int c = (int)(p & 0xffffu), r = (int)(p >> 16);
            int slot = atomicAdd(&cnt[c], 1);
            if (slot < CAP) ebuf[c * CAP + slot] = (unsigned short)r;
            else { int q = atomicAdd(ovf_cnt, 1); ovf[q] = p; }
        }
        return;
    }
    int xcd = blockIdx.x & 7;
    int t   = blockIdx.x >> 3;
    int lb  = t % LBUCK;
    int chunk = t / LBUCK;
    int b = xcd + 8 * lb;                  // bucket; b%8==xcd for L2 locality
    int n = min(bcnt[b], BCAP);
    int start = chunk * PBCH;
    if (start >= n) return;
    int end = min(start + PBCH, n);
    for (int idx = start + threadIdx.x; idx < end; idx += 256) {
        unsigned p = bbuf[b * BCAP + idx];
        int c = (int)(p & 0xffffu), r = (int)(p >> 16);
        int slot = atomicAdd(&cnt[c], 1);
        if (slot < CAP) ebuf[c * CAP + slot] = (unsigned short)r;
        else { int q = atomicAdd(ovf_cnt, 1); ovf[q] = p; }
    }
}

// ---- fused: gemm layer1 (blocks<GB) | dinv (GB..GB+DB) | rev scan (rest) -
__global__ void k_fused1(const float* __restrict__ X, const float* __restrict__ W,
                         unsigned short* __restrict__ Y0, unsigned short* __restrict__ Y1,
                         const int* __restrict__ cnt, float* __restrict__ dinv,
                         const int* __restrict__ j_idx, unsigned char* __restrict__ revb) {
    __shared__ float sW[64 * 64];
    __shared__ float sX[32 * 64];
    const int GB = N_NODES / 32;            // 1250
    const int DB = (N_NODES + 255) / 256;   // 157
    int bx = blockIdx.x;
    if (bx < GB) {
        int row0 = bx * 32;
        for (int t = threadIdx.x; t < 64 * 64; t += 256) sW[t] = W[t];
        for (int t = threadIdx.x; t < 32 * 64; t += 256) sX[t] = X[row0 * 64 + t];
        __syncthreads();
        int col = threadIdx.x & 63;
        int rl  = threadIdx.x >> 6;
        for (int r = rl; r < 32; r += 4) {
            float acc = 0.0f;
#pragma unroll
            for (int kk = 0; kk < 64; kk++) acc += sX[r * 64 + kk] * sW[kk * 64 + col];
            if (col < 32) Y0[(row0 + r) * 32 + col]      = f2bf(acc);
            else          Y1[(row0 + r) * 32 + col - 32] = f2bf(acc);
        }
    } else if (bx < GB + DB) {
        int n = (bx - GB) * 256 + threadIdx.x;
        if (n < N_NODES) dinv[n] = rsqrtf(1.0f + (float)cnt[n]);
    } else {
        int t = (bx - GB - DB) * 256 + threadIdx.x;   // NE*8 threads
        int e = t >> 3;
        int q = t & 7;
        int i = e / KNN;
        int j = j_idx[e];
        const int* jj = j_idx + j * KNN;
        int rt = 255;
        if (jj[q] == i) rt = q;
        if (jj[8 + q] == i) rt = min(rt, 8 + q);
        if (jj[16 + q] == i) rt = min(rt, 16 + q);
#pragma unroll
        for (int m = 1; m < 8; m <<= 1) rt = min(rt, __shfl_xor(rt, m));
        if (q == 0) revb[e] = (unsigned char)rt;
    }
}

// ---- Y = X @ W (layer 2), bf16 split-half output -------------------------
__global__ void k_gemm2(const unsigned short* __restrict__ X, const float* __restrict__ W,
                        unsigned short* __restrict__ Y0, unsigned short* __restrict__ Y1) {
    __shared__ float sW[64 * 64];
    __shared__ float sX[32 * 64];
    int row0 = blockIdx.x * 32;
    for (int t = threadIdx.x; t < 64 * 64; t += 256) sW[t] = W[t];
    for (int t = threadIdx.x; t < 32 * 64; t += 256) sX[t] = bf2f(X[row0 * 64 + t]);
    __syncthreads();
    int col = threadIdx.x & 63;
    int rl  = threadIdx.x >> 6;
    for (int r = rl; r < 32; r += 4) {
        float acc = 0.0f;
#pragma unroll
        for (int kk = 0; kk < 64; kk++) acc += sX[r * 64 + kk] * sW[kk * 64 + col];
        if (col < 32) Y0[(row0 + r) * 32 + col]      = f2bf(acc);
        else          Y1[(row0 + r) * 32 + col - 32] = f2bf(acc);
    }
}

// ---- pull aggregation, one wave per TWO nodes, packed dword gathers ------
// 16 lanes x dword = one 32-feature row; each 32-lane half gathers 2 rows
// per instruction (per-lane-variable shfl picks row 2d+g for subgroup g).
template<bool RELU, bool NORM>
__global__ void k_aggf2(const unsigned* __restrict__ X0p, const unsigned* __restrict__ X1p,
                        unsigned* __restrict__ outFp,   // packed full rows (layer 1), N*32 uints
                        unsigned* __restrict__ O0p,     // packed halves (layer 2), N*16 uints
                        unsigned* __restrict__ O1p,
                        const float* __restrict__ dinv, const int* __restrict__ cnt,
                        const unsigned short* __restrict__ ebuf, const float* __restrict__ bias,
                        const unsigned* __restrict__ ovf, const int* __restrict__ ovf_cnt) {
    int w = (blockIdx.x * 256 + threadIdx.x) >> 6;   // wave id, 2 nodes/wave
    int lane = threadIdx.x & 63;
    int half = lane >> 5, sl = lane & 31;
    int n = w * 2 + half;
    if (n >= N_NODES) return;
    int deg = cnt[n];
    int bucketed = min(deg, CAP);
    int nb0 = min(bucketed, 32);
    int nb1 = bucketed - nb0;

    int   r0v = 0, r1v = 0;
    float d0v = 0.0f, d1v = 0.0f;                    // 0 coef for idle lanes
    if (sl < nb0) { r0v = (int)ebuf[n * CAP + sl];      d0v = dinv[r0v]; }
    if (sl < nb1) { r1v = (int)ebuf[n * CAP + 32 + sl]; d1v = dinv[r1v]; }

    int g = sl >> 4;          // row subgroup 0/1
    int f = sl & 15;          // feature-pair index (features 2f, 2f+1)

    float a0lo = 0.f, a0hi = 0.f, a1lo = 0.f, a1hi = 0.f;
    int np0 = (nb0 + 1) >> 1;
    int np1 = (nb1 + 1) >> 1;

    // Phase A: features 0..31 from X0 (2.56 MB, L2-resident)
#pragma unroll 4
    for (int d = 0; d < np0; d++) {
        int   r = __shfl(r0v, 2 * d + g, 32);
        float c = __shfl(d0v, 2 * d + g, 32);
        unsigned u = X0p[r * 16 + f];
        a0lo += c * bflo(u); a0hi += c * bfhi(u);
    }
#pragma unroll 4
    for (int d = 0; d < np1; d++) {
        int   r = __shfl(r1v, 2 * d + g, 32);
        float c = __shfl(d1v, 2 * d + g, 32);
        unsigned u = X0p[r * 16 + f];
        a0lo += c * bflo(u); a0hi += c * bfhi(u);
    }
    // Phase B: features 32..63 from X1
#pragma unroll 4
    for (int d = 0; d < np0; d++) {
        int   r = __shfl(r0v, 2 * d + g, 32);
        float c = __shfl(d0v, 2 * d + g, 32);
        unsigned u = X1p[r * 16 + f];
        a1lo += c * bflo(u); a1hi += c * bfhi(u);
    }
#pragma unroll 4
    for (int d = 0; d < np1; d++) {
        int   r = __shfl(r1v, 2 * d + g, 32);
        float c = __shfl(d1v, 2 * d + g, 32);
        unsigned u = X1p[r * 16 + f];
        a1lo += c * bflo(u); a1hi += c * bfhi(u);
    }

    // CAP-overflow edges (normally none): scan ovf list, g==0 lanes only
    if (deg > CAP) {
        int m = ovf_cnt[0];
        for (int k = 0; k < m; k++) {
            unsigned p = ovf[k];
            if ((int)(p & 0xffffu) == n && g == 0) {
                int r = (int)(p >> 16);
                float c = dinv[r];
                unsigned u0 = X0p[r * 16 + f], u1 = X1p[r * 16 + f];
                a0lo += c * bflo(u0); a0hi += c * bfhi(u0);
                a1lo += c * bflo(u1); a1hi += c * bfhi(u1);
            }
        }
    }

    // merge the two row-subgroups
    a0lo += __shfl_xor(a0lo, 16, 32);
    a0hi += __shfl_xor(a0hi, 16, 32);
    a1lo += __shfl_xor(a1lo, 16, 32);
    a1hi += __shfl_xor(a1hi, 16, 32);

    float di = dinv[n];
    unsigned s0 = X0p[n * 16 + f], s1 = X1p[n * 16 + f];
    float2 bA = ((const float2*)bias)[f];
    float2 bB = ((const float2*)bias)[16 + f];
    float v0lo = di * a0lo + di * di * bflo(s0) + bA.x;
    float v0hi = di * a0hi + di * di * bfhi(s0) + bA.y;
    float v1lo = di * a1lo + di * di * bflo(s1) + bB.x;
    float v1hi = di * a1hi + di * di * bfhi(s1) + bB.y;
    if (RELU) {
        v0lo = fmaxf(v0lo, 0.f); v0hi = fmaxf(v0hi, 0.f);
        v1lo = fmaxf(v1lo, 0.f); v1hi = fmaxf(v1hi, 0.f);
    }
    if (NORM) {
        float s = v0lo * v0lo + v0hi * v0hi + v1lo * v1lo + v1hi * v1hi;
        s += __shfl_xor(s, 1, 32); s += __shfl_xor(s, 2, 32);
        s += __shfl_xor(s, 4, 32); s += __shfl_xor(s, 8, 32);
        float inv = 1.0f / fmaxf(sqrtf(s), 1e-12f);
        v0lo *= inv; v0hi *= inv; v1lo *= inv; v1hi *= inv;
        if (g == 0) {
            O0p[n * 16 + f] = pack2(v0lo, v0hi);
            O1p[n * 16 + f] = pack2(v1lo, v1hi);
        }
    } else {
        if (g == 0) {
            outFp[n * 32 + f]      = pack2(v0lo, v0hi);
            outFp[n * 32 + 16 + f] = pack2(v1lo, v1hi);
        }
    }
}

// ---- pass A: partial dot over half 0; one uint4 row-gather per lane ------
// 8 lanes/edge: lanes 0-3 fetch i's row quarters, 4-7 fetch j's; shfl_xor(4)
// aligns partners; reduce over the 4 feature-quarters.
__global__ void k_dot0(const uint4* __restrict__ h0q, const int* __restrict__ j_idx,
                       float* __restrict__ pdot) {
    int t = blockIdx.x * 256 + threadIdx.x;   // NE*8 threads
    int e = t >> 3;
    int q = t & 7;
    int g = q >> 2, f = q & 3;
    int i = e / KNN;
    int j = j_idx[e];
    int node = g ? j : i;
    uint4 v = h0q[node * 4 + f];
    uint4 p;
    p.x = __shfl_xor(v.x, 4); p.y = __shfl_xor(v.y, 4);
    p.z = __shfl_xor(v.z, 4); p.w = __shfl_xor(v.w, 4);
    float s = bflo(v.x) * bflo(p.x) + bfhi(v.x) * bfhi(p.x)
            + bflo(v.y) * bflo(p.y) + bfhi(v.y) * bfhi(p.y)
            + bflo(v.z) * bflo(p.z) + bfhi(v.z) * bfhi(p.z)
            + bflo(v.w) * bflo(p.w) + bfhi(v.w) * bfhi(p.w);
    s += __shfl_xor(s, 1);
    s += __shfl_xor(s, 2);
    if (q == 0) pdot[e] = s;
}

// ---- pass B: half 1 dot + finalize + symmetrize (NO atomics) -------------
__global__ void k_edgesym2(const uint4* __restrict__ h1q, const float* __restrict__ pdot,
                           const float* __restrict__ s_d, const int* __restrict__ j_idx,
                           const unsigned char* __restrict__ revb,
                           float* __restrict__ outS) {   // d_out + 2E, holds vals_s [2E]
    int t = blockIdx.x * 256 + threadIdx.x;   // NE*8 threads
    int e = t >> 3;
    int q = t & 7;
    int g = q >> 2, f = q & 3;
    int i = e / KNN;
    int j = j_idx[e];
    int node = g ? j : i;
    uint4 v = h1q[node * 4 + f];
    uint4 p;
    p.x = __shfl_xor(v.x, 4); p.y = __shfl_xor(v.y, 4);
    p.z = __shfl_xor(v.z, 4); p.w = __shfl_xor(v.w, 4);
    float s = bflo(v.x) * bflo(p.x) + bfhi(v.x) * bfhi(p.x)
            + bflo(v.y) * bflo(p.y) + bfhi(v.y) * bfhi(p.y)
            + bflo(v.z) * bflo(p.z) + bfhi(v.z) * bfhi(p.z)
            + bflo(v.w) * bflo(p.w) + bfhi(v.w) * bfhi(p.w);
    s += __shfl_xor(s, 1);
    s += __shfl_xor(s, 2);
    if (q == 0) {
        s += pdot[e];
        float base = OMEGA * fmaxf(s, 0.0f);
        int rt = revb[e];
        float vv, v2;
        if (rt != 255) {                     // reverse edge exists (rare)
            int rev = j * KNN + rt;
            vv = base + 0.5f * (1.0f - OMEGA) * (s_d[e] + s_d[rev]);
            v2 = 0.0f;
        } else {
            vv = base + (1.0f - OMEGA) * s_d[e];
            v2 = vv;
        }
        outS[e] = vv;
        outS[NE + e] = v2;
    }
}

// ---- binned in-edge accumulation + fused dinv2 ---------------------------
// Block b owns nodes [b*512,(b+1)*512): LDS-accumulate v2 over its learner
// in-edges, add the contiguous out-edge segment sums, emit dinv2 directly.
__global__ void k_jagg(const unsigned* __restrict__ jbbuf, const int* __restrict__ jbcnt,
                       const float* __restrict__ outS, float* __restrict__ dinv2,
                       const unsigned* __restrict__ jovf, const int* __restrict__ jovf_cnt,
                       const int* __restrict__ j_idx) {
    __shared__ float ld[512];
    int b = blockIdx.x;
    int tid = threadIdx.x;                   // 1024 threads
    if (tid < 512) ld[tid] = 0.0f;
    __syncthreads();
    const float* outSv2 = outS + NE;
    int n = min(jbcnt[b], JBCAP);
    for (int idx = tid; idx < n; idx += 1024) {
        unsigned p = jbbuf[b * JBCAP + idx];
        atomicAdd(&ld[p >> 20], outSv2[p & 0xFFFFFu]);
    }
    int m = jovf_cnt[0];                     // learner bin overflow (normally 0)
    for (int t2 = tid; t2 < m; t2 += 1024) {
        int e = (int)(jovf[t2] & 0xFFFFFu);
        int j = j_idx[e];
        if ((j >> 9) == b) atomicAdd(&ld[j & 511], outSv2[e]);
    }
    __syncthreads();
    if (tid < 512) {
        int node = b * 512 + tid;
        if (node < N_NODES) {
            float d = ld[tid];
            const float* pp = outS + node * KNN;
#pragma unroll
            for (int qq = 0; qq < KNN; qq++) d += pp[qq];
            dinv2[node] = (d > 0.0f) ? rsqrtf(fmaxf(d, 1e-12f)) : 0.0f;
        }
    }
}

// ---- final normalization: vals_norm = dinv2[r] * vals_s * dinv2[c] -------
__global__ void k_norm(const float* __restrict__ outS, const float* __restrict__ dinv2,
                       const int* __restrict__ j_idx, float* __restrict__ out) {
    int t = blockIdx.x * 256 + threadIdx.x;   // 2*NE threads
    int r, c;
    if (t < NE) { r = t / KNN; c = j_idx[t]; }
    else        { int e = t - NE; r = j_idx[e]; c = e / KNN; }
    out[t] = dinv2[r] * outS[t] * dinv2[c];
}

extern "C" void kernel_launch(void* const* d_in, const int* in_sizes, int n_in,
                              void* d_out, int out_size, void* d_ws, size_t ws_size,
                              hipStream_t stream) {
    const float* features = (const float*)d_in[0];
    const float* W1       = (const float*)d_in[1];
    const float* b1       = (const float*)d_in[2];
    const float* W2       = (const float*)d_in[3];
    const float* b2       = (const float*)d_in[4];
    const float* s_d      = (const float*)d_in[5];
    const int*   adj_row  = (const int*)d_in[6];
    const int*   adj_col  = (const int*)d_in[7];
    const int*   j_idx    = (const int*)d_in[9];
    float* out = (float*)d_out;

    const int N64 = N_NODES * 64;
    const int N32 = N_NODES * 32;
    // Workspace layout (zero region first):
    // [cnt N][ovfcnts 16][bcnt 80][jbcnt 80]  <- memset 0
    // [dinv N][dinv2 N][A0 N32 us][A1 N32 us][B16 N64 us][H0 N32 us][H1 N32 us]
    // [ebuf N*CAP us][ovf NE u][revb NE uc][bbuf][jbbuf][ovf2 NE u][jovf NE u]
    // pdot aliases bbuf (dead after k_scatter2; pdot born at k_dot0)
    int*   cnt     = (int*)d_ws;
    int*   ovfcnts = cnt + N_NODES;          // [0]=CAP ovf, [4]=adj bin ovf, [8]=learner bin ovf
    int*   bcnt    = ovfcnts + 16;
    int*   jbcnt   = bcnt + NBUCK;
    float* dinv    = (float*)(jbcnt + NBUCK);
    float* dinv2   = dinv + N_NODES;
    unsigned short* A0  = (unsigned short*)(dinv2 + N_NODES);
    unsigned short* A1  = A0 + N32;
    unsigned short* B16 = A1 + N32;
    unsigned short* H0  = B16 + N64;
    unsigned short* H1  = H0 + N32;
    unsigned short* ebuf = H1 + N32;             // N*CAP ushorts
    unsigned* ovf    = (unsigned*)(ebuf + N_NODES * CAP);
    unsigned char* revb = (unsigned char*)(ovf + NE);
    unsigned* bbuf   = (unsigned*)(revb + NE);   // NBUCK*BCAP
    unsigned* jbbuf  = bbuf + NBUCK * BCAP;      // NBUCK*JBCAP
    unsigned* ovf2   = jbbuf + NBUCK * JBCAP;    // NE
    unsigned* jovf   = ovf2 + NE;                // NE
    float*    pdot   = (float*)bbuf;             // alias

    // Re-init (ws is poisoned 0xAA before every call)
    size_t zero_bytes = (size_t)(N_NODES + 16 + 2 * NBUCK) * 4;
    hipMemsetAsync(cnt, 0, zero_bytes, stream);

    // Bin both edge sets, then XCD-affine scatter (adj) -> ebuf + cnt
    const int NB_ADJ = (NE + 256 * EPT - 1) / (256 * EPT);
    k_bin<<<2 * NB_ADJ, 256, 0, stream>>>(adj_row, adj_col, j_idx,
                                          bcnt, bbuf, ovf2, ovfcnts + 4,
                                          jbcnt, jbbuf, jovf, ovfcnts + 8);
    k_scatter2<<<8 * LBUCK * (BCAP / PBCH) + 8, 256, 0, stream>>>(bbuf, bcnt, cnt, ebuf,
                                                                  ovf, ovfcnts, ovf2, ovfcnts + 4);

    // Fused: gemm layer1 + dinv + reverse-edge scan
    const int GB = N_NODES / 32, DB = (N_NODES + 255) / 256, RB = NE * 8 / 256;
    k_fused1<<<GB + DB + RB, 256, 0, stream>>>(features, W1, A0, A1, cnt, dinv, j_idx, revb);

    // Layer 1 aggregate (overflow handled inline)
    k_aggf2<true, false><<<(N_NODES / 2 * 64 + 255) / 256, 256, 0, stream>>>(
        (const unsigned*)A0, (const unsigned*)A1, (unsigned*)B16, nullptr, nullptr,
        dinv, cnt, ebuf, b1, ovf, ovfcnts);

    // Layer 2
    k_gemm2<<<N_NODES / 32, 256, 0, stream>>>(B16, W2, A0, A1);
    k_aggf2<false, true><<<(N_NODES / 2 * 64 + 255) / 256, 256, 0, stream>>>(
        (const unsigned*)A0, (const unsigned*)A1, nullptr, (unsigned*)H0, (unsigned*)H1,
        dinv, cnt, ebuf, b2, ovf, ovfcnts);

    // Edge scores: half-0 partial dots, then half-1 + symmetrize (atomic-free)
    float* outS = out + 2 * NE;
    k_dot0<<<NE * 8 / 256, 256, 0, stream>>>((const uint4*)H0, j_idx, pdot);
    k_edgesym2<<<NE * 8 / 256, 256, 0, stream>>>((const uint4*)H1, pdot, s_d, j_idx, revb, outS);

    // Binned in-edge accumulation + dinv2, then final normalize
    k_jagg<<<NBUCK, 1024, 0, stream>>>(jbbuf, jbcnt, outS, dinv2, jovf, ovfcnts + 8, j_idx);
    k_norm<<<2 * NE / 256, 256, 0, stream>>>(outS, dinv2, j_idx, out);
}

// Round 10
// 292.946 us; speedup vs baseline: 1.1249x; 1.1249x over previous
//
#include <hip/hip_runtime.h>

// Problem constants (match reference)
#define N_NODES 40000
#define ISIZE   64
#define KNN     24
#define NE      (N_NODES * KNN)      // 960000 edges (= E_ADJ as well)
#define OMEGA   0.9f
#define CAP     64                   // per-node bucket capacity (max deg ~46)
#define NBUCK   80                   // buckets of 512 nodes (idx>>9)
#define LBUCK   10                   // buckets per XCD (NBUCK/8)
#define BCAP    16384                // adj edges per bucket capacity (mean 12288)
#define JBCAP   16384                // learner edges per bucket capacity
#define EPT     8                    // edges per thread in k_bin
#define PBCH    512                  // edges per block in k_scatter2

// ---- bf16 helpers (storage-only precision; all math in fp32) -------------
__device__ __forceinline__ float bf2f(unsigned short s) {
    return __uint_as_float(((unsigned)s) << 16);
}
__device__ __forceinline__ unsigned short f2bf(float f) {  // round-nearest-even
    unsigned u = __float_as_uint(f);
    u += 0x7fffu + ((u >> 16) & 1u);
    return (unsigned short)(u >> 16);
}
__device__ __forceinline__ float bflo(unsigned u) { return __uint_as_float(u << 16); }
__device__ __forceinline__ float bfhi(unsigned u) { return __uint_as_float(u & 0xffff0000u); }
__device__ __forceinline__ unsigned pack2(float lo, float hi) {
    return (unsigned)f2bf(lo) | ((unsigned)f2bf(hi) << 16);
}

// ---- bin BOTH edge sets: adj by col (pack r<<16|c), learner by j (pack (j&511)<<20|e)
__global__ void k_bin(const int* __restrict__ row, const int* __restrict__ col,
                      const int* __restrict__ j_idx,
                      int* __restrict__ bcnt, unsigned* __restrict__ bbuf,
                      unsigned* __restrict__ ovf2, int* __restrict__ ovf2_cnt,
                      int* __restrict__ jbcnt, unsigned* __restrict__ jbbuf,
                      unsigned* __restrict__ jovf, int* __restrict__ jovf_cnt) {
    __shared__ int lcnt[NBUCK];
    __shared__ int lbase[NBUCK];
    const int NB_ADJ = (NE + 256 * EPT - 1) / (256 * EPT);
    int tid = threadIdx.x;
    bool adj = (int)blockIdx.x < NB_ADJ;
    int blk = adj ? blockIdx.x : blockIdx.x - NB_ADJ;
    for (int b = tid; b < NBUCK; b += 256) lcnt[b] = 0;
    __syncthreads();
    int e0 = blk * (256 * EPT);
    int myslot[EPT]; int myb[EPT]; unsigned myp[EPT];
    for (int k = 0; k < EPT; k++) {
        int e = e0 + k * 256 + tid;
        if (e < NE) {
            int b; unsigned p;
            if (adj) { int r = row[e], c = col[e]; b = c >> 9; p = ((unsigned)r << 16) | (unsigned)c; }
            else     { int j = j_idx[e];           b = j >> 9; p = ((unsigned)(j & 511) << 20) | (unsigned)e; }
            myb[k] = b; myp[k] = p;
            myslot[k] = atomicAdd(&lcnt[b], 1);
        } else myb[k] = -1;
    }
    __syncthreads();
    int* gcnt = adj ? bcnt : jbcnt;
    for (int b = tid; b < NBUCK; b += 256)
        lbase[b] = (lcnt[b] > 0) ? atomicAdd(&gcnt[b], lcnt[b]) : 0;
    __syncthreads();
    unsigned* gbuf = adj ? bbuf : jbbuf;
    unsigned* govf = adj ? ovf2 : jovf;
    int* gocnt = adj ? ovf2_cnt : jovf_cnt;
    int capb = adj ? BCAP : JBCAP;
    for (int k = 0; k < EPT; k++) {
        if (myb[k] < 0) continue;
        int pos = lbase[myb[k]] + myslot[k];
        if (pos < capb) gbuf[myb[k] * capb + pos] = myp[k];
        else { int p = atomicAdd(gocnt, 1); govf[p] = myp[k]; }
    }
}

// ---- XCD-affine scatter into ebuf (+ adj-bin-overflow tail blocks) -------
__global__ void k_scatter2(const unsigned* __restrict__ bbuf, const int* __restrict__ bcnt,
                           int* __restrict__ cnt, unsigned short* __restrict__ ebuf,
                           unsigned* __restrict__ ovf, int* __restrict__ ovf_cnt,
                           const unsigned* __restrict__ ovf2, const int* __restrict__ ovf2_cnt) {
    const int MAIN = 8 * LBUCK * (BCAP / PBCH);   // 2560
    if ((int)blockIdx.x >= MAIN) {                // adj bin-overflow fallback (normally 0)
        int m = ovf2_cnt[0];
        for (int t = (blockIdx.x - MAIN) * 256 + threadIdx.x; t < m; t += 8 * 256) {
            unsigned p = ovf2[t];
            int c = (int)(p & 0xffffu), r = (int)(p >> 16);
            int slot = atomicAdd(&cnt[c], 1);
            if (slot < CAP) ebuf[c * CAP + slot] = (unsigned short)r;
            else { int q = atomicAdd(ovf_cnt, 1); ovf[q] = p; }
        }
        return;
    }
    int xcd = blockIdx.x & 7;
    int t   = blockIdx.x >> 3;
    int lb  = t % LBUCK;
    int chunk = t / LBUCK;
    int b = xcd + 8 * lb;                  // bucket; b%8==xcd for L2 locality
    int n = min(bcnt[b], BCAP);
    int start = chunk * PBCH;
    if (start >= n) return;
    int end = min(start + PBCH, n);
    for (int idx = start + threadIdx.x; idx < end; idx += 256) {
        unsigned p = bbuf[b * BCAP + idx];
        int c = (int)(p & 0xffffu), r = (int)(p >> 16);
        int slot = atomicAdd(&cnt[c], 1);
        if (slot < CAP) ebuf[c * CAP + slot] = (unsigned short)r;
        else { int q = atomicAdd(ovf_cnt, 1); ovf[q] = p; }
    }
}

// ---- fused: gemm layer1 (blocks<GB) | dinv (GB..GB+DB) | rev scan (rest) -
__global__ void k_fused1(const float* __restrict__ X, const float* __restrict__ W,
                         unsigned short* __restrict__ Y0, unsigned short* __restrict__ Y1,
                         const int* __restrict__ cnt, float* __restrict__ dinv,
                         const int* __restrict__ j_idx, unsigned char* __restrict__ revb) {
    __shared__ float sW[64 * 64];
    __shared__ float sX[32 * 64];
    const int GB = N_NODES / 32;            // 1250
    const int DB = (N_NODES + 255) / 256;   // 157
    int bx = blockIdx.x;
    if (bx < GB) {
        int row0 = bx * 32;
        for (int t = threadIdx.x; t < 1024; t += 256)
            ((float4*)sW)[t] = ((const float4*)W)[t];
        for (int t = threadIdx.x; t < 512; t += 256)
            ((float4*)sX)[t] = ((const float4*)(X + row0 * 64))[t];
        __syncthreads();
        int col = threadIdx.x & 63;
        int rl  = threadIdx.x >> 6;
        for (int r = rl; r < 32; r += 4) {
            float acc = 0.0f;
#pragma unroll
            for (int kk = 0; kk < 64; kk++) acc += sX[r * 64 + kk] * sW[kk * 64 + col];
            if (col < 32) Y0[(row0 + r) * 32 + col]      = f2bf(acc);
            else          Y1[(row0 + r) * 32 + col - 32] = f2bf(acc);
        }
    } else if (bx < GB + DB) {
        int n = (bx - GB) * 256 + threadIdx.x;
        if (n < N_NODES) dinv[n] = rsqrtf(1.0f + (float)cnt[n]);
    } else {
        int t = (bx - GB - DB) * 256 + threadIdx.x;   // NE*8 threads
        int e = t >> 3;
        int q = t & 7;
        int i = e / KNN;
        int j = j_idx[e];
        const int* jj = j_idx + j * KNN;
        int rt = 255;
        if (jj[q] == i) rt = q;
        if (jj[8 + q] == i) rt = min(rt, 8 + q);
        if (jj[16 + q] == i) rt = min(rt, 16 + q);
#pragma unroll
        for (int m = 1; m < 8; m <<= 1) rt = min(rt, __shfl_xor(rt, m));
        if (q == 0) revb[e] = (unsigned char)rt;
    }
}

// ---- Y = X @ W (layer 2), bf16 split-half output -------------------------
__global__ void k_gemm2(const unsigned short* __restrict__ X, const float* __restrict__ W,
                        unsigned short* __restrict__ Y0, unsigned short* __restrict__ Y1) {
    __shared__ float sW[64 * 64];
    __shared__ float sX[32 * 64];
    int row0 = blockIdx.x * 32;
    for (int t = threadIdx.x; t < 1024; t += 256)
        ((float4*)sW)[t] = ((const float4*)W)[t];
    for (int t = threadIdx.x; t < 512; t += 256) {
        uint2 u = ((const uint2*)(X + row0 * 64))[t];
        float4 v = make_float4(bflo(u.x), bfhi(u.x), bflo(u.y), bfhi(u.y));
        ((float4*)sX)[t] = v;
    }
    __syncthreads();
    int col = threadIdx.x & 63;
    int rl  = threadIdx.x >> 6;
    for (int r = rl; r < 32; r += 4) {
        float acc = 0.0f;
#pragma unroll
        for (int kk = 0; kk < 64; kk++) acc += sX[r * 64 + kk] * sW[kk * 64 + col];
        if (col < 32) Y0[(row0 + r) * 32 + col]      = f2bf(acc);
        else          Y1[(row0 + r) * 32 + col - 32] = f2bf(acc);
    }
}

// ---- pull aggregation: 2 nodes/wave, uint2 gathers, interleaved halves ---
// 32-lane half per node: 4 row-groups (g) x 8 uint2 feature slots (f).
// Each iteration gathers 4 rows x both halves -> 2 x 512B loads in flight,
// fully unrolled: ~12 concurrent loads/wave at deg 24 (latency-bound fix).
template<bool RELU, bool NORM>
__global__ void k_aggf3(const uint2* __restrict__ X0p2, const uint2* __restrict__ X1p2,
                        uint2* __restrict__ outFp2,   // packed full rows (layer 1), N*16 uint2
                        uint2* __restrict__ O0p2,     // packed halves (layer 2), N*8 uint2
                        uint2* __restrict__ O1p2,
                        const float* __restrict__ dinv, const int* __restrict__ cnt,
                        const unsigned short* __restrict__ ebuf, const float* __restrict__ bias,
                        const unsigned* __restrict__ ovf, const int* __restrict__ ovf_cnt) {
    int w = (blockIdx.x * 256 + threadIdx.x) >> 6;   // wave id, 2 nodes/wave
    int lane = threadIdx.x & 63;
    int half = lane >> 5, sl = lane & 31;
    int n = w * 2 + half;
    if (n >= N_NODES) return;
    int deg = cnt[n];
    int bucketed = min(deg, CAP);
    int nb0 = min(bucketed, 32);
    int nb1 = bucketed - nb0;

    int   r0v = 0, r1v = 0;
    float d0v = 0.0f, d1v = 0.0f;                    // 0 coef for idle entries
    if (sl < nb0) { r0v = (int)ebuf[n * CAP + sl];      d0v = dinv[r0v]; }
    if (sl < nb1) { r1v = (int)ebuf[n * CAP + 32 + sl]; d1v = dinv[r1v]; }

    int g = sl >> 3;          // row subgroup 0..3
    int f = sl & 7;           // uint2 slot: features 4f..4f+3 of each half

    float a0 = 0.f, a1 = 0.f, a2 = 0.f, a3 = 0.f;
    float a4 = 0.f, a5 = 0.f, a6 = 0.f, a7 = 0.f;
    int np0 = (nb0 + 3) >> 2;
    int np1 = (nb1 + 3) >> 2;

#pragma unroll 8
    for (int d = 0; d < np0; d++) {
        int   q = 4 * d + g;
        int   r = __shfl(r0v, q, 32);
        float c = __shfl(d0v, q, 32);
        uint2 u0 = X0p2[r * 8 + f];
        uint2 u1 = X1p2[r * 8 + f];
        a0 += c * bflo(u0.x); a1 += c * bfhi(u0.x);
        a2 += c * bflo(u0.y); a3 += c * bfhi(u0.y);
        a4 += c * bflo(u1.x); a5 += c * bfhi(u1.x);
        a6 += c * bflo(u1.y); a7 += c * bfhi(u1.y);
    }
#pragma unroll 8
    for (int d = 0; d < np1; d++) {
        int   q = 4 * d + g;
        int   r = __shfl(r1v, q, 32);
        float c = __shfl(d1v, q, 32);
        uint2 u0 = X0p2[r * 8 + f];
        uint2 u1 = X1p2[r * 8 + f];
        a0 += c * bflo(u0.x); a1 += c * bfhi(u0.x);
        a2 += c * bflo(u0.y); a3 += c * bfhi(u0.y);
        a4 += c * bflo(u1.x); a5 += c * bfhi(u1.x);
        a6 += c * bflo(u1.y); a7 += c * bfhi(u1.y);
    }

    // CAP-overflow edges (normally none): scan ovf list, g==0 lanes only
    if (deg > CAP) {
        int m = ovf_cnt[0];
        for (int k = 0; k < m; k++) {
            unsigned p = ovf[k];
            if ((int)(p & 0xffffu) == n && g == 0) {
                int r = (int)(p >> 16);
                float c = dinv[r];
                uint2 u0 = X0p2[r * 8 + f], u1 = X1p2[r * 8 + f];
                a0 += c * bflo(u0.x); a1 += c * bfhi(u0.x);
                a2 += c * bflo(u0.y); a3 += c * bfhi(u0.y);
                a4 += c * bflo(u1.x); a5 += c * bfhi(u1.x);
                a6 += c * bflo(u1.y); a7 += c * bfhi(u1.y);
            }
        }
    }

    // merge the 4 row-subgroups (xor 8, then 16 within the 32-lane half)
    a0 += __shfl_xor(a0, 8, 32);  a1 += __shfl_xor(a1, 8, 32);
    a2 += __shfl_xor(a2, 8, 32);  a3 += __shfl_xor(a3, 8, 32);
    a4 += __shfl_xor(a4, 8, 32);  a5 += __shfl_xor(a5, 8, 32);
    a6 += __shfl_xor(a6, 8, 32);  a7 += __shfl_xor(a7, 8, 32);
    a0 += __shfl_xor(a0, 16, 32); a1 += __shfl_xor(a1, 16, 32);
    a2 += __shfl_xor(a2, 16, 32); a3 += __shfl_xor(a3, 16, 32);
    a4 += __shfl_xor(a4, 16, 32); a5 += __shfl_xor(a5, 16, 32);
    a6 += __shfl_xor(a6, 16, 32); a7 += __shfl_xor(a7, 16, 32);

    float di = dinv[n];
    uint2 s0 = X0p2[n * 8 + f], s1 = X1p2[n * 8 + f];
    float4 bA = ((const float4*)bias)[f];
    float4 bB = ((const float4*)(bias + 32))[f];
    float dd = di * di;
    float v0 = di * a0 + dd * bflo(s0.x) + bA.x;
    float v1 = di * a1 + dd * bfhi(s0.x) + bA.y;
    float v2 = di * a2 + dd * bflo(s0.y) + bA.z;
    float v3 = di * a3 + dd * bfhi(s0.y) + bA.w;
    float v4 = di * a4 + dd * bflo(s1.x) + bB.x;
    float v5 = di * a5 + dd * bfhi(s1.x) + bB.y;
    float v6 = di * a6 + dd * bflo(s1.y) + bB.z;
    float v7 = di * a7 + dd * bfhi(s1.y) + bB.w;
    if (RELU) {
        v0 = fmaxf(v0, 0.f); v1 = fmaxf(v1, 0.f); v2 = fmaxf(v2, 0.f); v3 = fmaxf(v3, 0.f);
        v4 = fmaxf(v4, 0.f); v5 = fmaxf(v5, 0.f); v6 = fmaxf(v6, 0.f); v7 = fmaxf(v7, 0.f);
    }
    if (NORM) {
        float s = v0 * v0 + v1 * v1 + v2 * v2 + v3 * v3
                + v4 * v4 + v5 * v5 + v6 * v6 + v7 * v7;
        s += __shfl_xor(s, 1, 32); s += __shfl_xor(s, 2, 32); s += __shfl_xor(s, 4, 32);
        float inv = 1.0f / fmaxf(sqrtf(s), 1e-12f);
        v0 *= inv; v1 *= inv; v2 *= inv; v3 *= inv;
        v4 *= inv; v5 *= inv; v6 *= inv; v7 *= inv;
        if (g == 0) {
            O0p2[n * 8 + f] = make_uint2(pack2(v0, v1), pack2(v2, v3));
            O1p2[n * 8 + f] = make_uint2(pack2(v4, v5), pack2(v6, v7));
        }
    } else {
        if (g == 0) {
            outFp2[n * 16 + f]     = make_uint2(pack2(v0, v1), pack2(v2, v3));
            outFp2[n * 16 + 8 + f] = make_uint2(pack2(v4, v5), pack2(v6, v7));
        }
    }
}

// ---- pass A: partial dot over half 0; one uint4 row-gather per lane ------
__global__ void k_dot0(const uint4* __restrict__ h0q, const int* __restrict__ j_idx,
                       float* __restrict__ pdot) {
    int t = blockIdx.x * 256 + threadIdx.x;   // NE*8 threads
    int e = t >> 3;
    int q = t & 7;
    int g = q >> 2, f = q & 3;
    int i = e / KNN;
    int j = j_idx[e];
    int node = g ? j : i;
    uint4 v = h0q[node * 4 + f];
    uint4 p;
    p.x = __shfl_xor(v.x, 4); p.y = __shfl_xor(v.y, 4);
    p.z = __shfl_xor(v.z, 4); p.w = __shfl_xor(v.w, 4);
    float s = bflo(v.x) * bflo(p.x) + bfhi(v.x) * bfhi(p.x)
            + bflo(v.y) * bflo(p.y) + bfhi(v.y) * bfhi(p.y)
            + bflo(v.z) * bflo(p.z) + bfhi(v.z) * bfhi(p.z)
            + bflo(v.w) * bflo(p.w) + bfhi(v.w) * bfhi(p.w);
    s += __shfl_xor(s, 1);
    s += __shfl_xor(s, 2);
    if (q == 0) pdot[e] = s;
}

// ---- pass B: half 1 dot + finalize + symmetrize (NO atomics) -------------
__global__ void k_edgesym2(const uint4* __restrict__ h1q, const float* __restrict__ pdot,
                           const float* __restrict__ s_d, const int* __restrict__ j_idx,
                           const unsigned char* __restrict__ revb,
                           float* __restrict__ outS) {   // d_out + 2E, holds vals_s [2E]
    int t = blockIdx.x * 256 + threadIdx.x;   // NE*8 threads
    int e = t >> 3;
    int q = t & 7;
    int g = q >> 2, f = q & 3;
    int i = e / KNN;
    int j = j_idx[e];
    int node = g ? j : i;
    uint4 v = h1q[node * 4 + f];
    uint4 p;
    p.x = __shfl_xor(v.x, 4); p.y = __shfl_xor(v.y, 4);
    p.z = __shfl_xor(v.z, 4); p.w = __shfl_xor(v.w, 4);
    float s = bflo(v.x) * bflo(p.x) + bfhi(v.x) * bfhi(p.x)
            + bflo(v.y) * bflo(p.y) + bfhi(v.y) * bfhi(p.y)
            + bflo(v.z) * bflo(p.z) + bfhi(v.z) * bfhi(p.z)
            + bflo(v.w) * bflo(p.w) + bfhi(v.w) * bfhi(p.w);
    s += __shfl_xor(s, 1);
    s += __shfl_xor(s, 2);
    if (q == 0) {
        s += pdot[e];
        float base = OMEGA * fmaxf(s, 0.0f);
        int rt = revb[e];
        float vv, v2;
        if (rt != 255) {                     // reverse edge exists (rare)
            int rev = j * KNN + rt;
            vv = base + 0.5f * (1.0f - OMEGA) * (s_d[e] + s_d[rev]);
            v2 = 0.0f;
        } else {
            vv = base + (1.0f - OMEGA) * s_d[e];
            v2 = vv;
        }
        outS[e] = vv;
        outS[NE + e] = v2;
    }
}

// ---- binned in-edge accumulation + fused dinv2 ---------------------------
__global__ void k_jagg(const unsigned* __restrict__ jbbuf, const int* __restrict__ jbcnt,
                       const float* __restrict__ outS, float* __restrict__ dinv2,
                       const unsigned* __restrict__ jovf, const int* __restrict__ jovf_cnt,
                       const int* __restrict__ j_idx) {
    __shared__ float ld[512];
    int b = blockIdx.x;
    int tid = threadIdx.x;                   // 1024 threads
    if (tid < 512) ld[tid] = 0.0f;
    __syncthreads();
    const float* outSv2 = outS + NE;
    int n = min(jbcnt[b], JBCAP);
    for (int idx = tid; idx < n; idx += 1024) {
        unsigned p = jbbuf[b * JBCAP + idx];
        atomicAdd(&ld[p >> 20], outSv2[p & 0xFFFFFu]);
    }
    int m = jovf_cnt[0];                     // learner bin overflow (normally 0)
    for (int t2 = tid; t2 < m; t2 += 1024) {
        int e = (int)(jovf[t2] & 0xFFFFFu);
        int j = j_idx[e];
        if ((j >> 9) == b) atomicAdd(&ld[j & 511], outSv2[e]);
    }
    __syncthreads();
    if (tid < 512) {
        int node = b * 512 + tid;
        if (node < N_NODES) {
            float d = ld[tid];
            const float* pp = outS + node * KNN;
#pragma unroll
            for (int qq = 0; qq < KNN; qq++) d += pp[qq];
            dinv2[node] = (d > 0.0f) ? rsqrtf(fmaxf(d, 1e-12f)) : 0.0f;
        }
    }
}

// ---- final normalization: vals_norm = dinv2[r] * vals_s * dinv2[c] -------
__global__ void k_norm(const float* __restrict__ outS, const float* __restrict__ dinv2,
                       const int* __restrict__ j_idx, float* __restrict__ out) {
    int t = blockIdx.x * 256 + threadIdx.x;   // 2*NE threads
    int r, c;
    if (t < NE) { r = t / KNN; c = j_idx[t]; }
    else        { int e = t - NE; r = j_idx[e]; c = e / KNN; }
    out[t] = dinv2[r] * outS[t] * dinv2[c];
}

extern "C" void kernel_launch(void* const* d_in, const int* in_sizes, int n_in,
                              void* d_out, int out_size, void* d_ws, size_t ws_size,
                              hipStream_t stream) {
    const float* features = (const float*)d_in[0];
    const float* W1       = (const float*)d_in[1];
    const float* b1       = (const float*)d_in[2];
    const float* W2       = (const float*)d_in[3];
    const float* b2       = (const float*)d_in[4];
    const float* s_d      = (const float*)d_in[5];
    const int*   adj_row  = (const int*)d_in[6];
    const int*   adj_col  = (const int*)d_in[7];
    const int*   j_idx    = (const int*)d_in[9];
    float* out = (float*)d_out;

    const int N64 = N_NODES * 64;
    const int N32 = N_NODES * 32;
    // Workspace layout (zero region first):
    // [cnt N][ovfcnts 16][bcnt 80][jbcnt 80]  <- memset 0
    // [dinv N][dinv2 N][A0 N32 us][A1 N32 us][B16 N64 us][H0 N32 us][H1 N32 us]
    // [ebuf N*CAP us][ovf NE u][revb NE uc][bbuf][jbbuf][ovf2 NE u][jovf NE u]
    // pdot aliases bbuf (dead after k_scatter2; pdot born at k_dot0)
    int*   cnt     = (int*)d_ws;
    int*   ovfcnts = cnt + N_NODES;          // [0]=CAP ovf, [4]=adj bin ovf, [8]=learner bin ovf
    int*   bcnt    = ovfcnts + 16;
    int*   jbcnt   = bcnt + NBUCK;
    float* dinv    = (float*)(jbcnt + NBUCK);
    float* dinv2   = dinv + N_NODES;
    unsigned short* A0  = (unsigned short*)(dinv2 + N_NODES);
    unsigned short* A1  = A0 + N32;
    unsigned short* B16 = A1 + N32;
    unsigned short* H0  = B16 + N64;
    unsigned short* H1  = H0 + N32;
    unsigned short* ebuf = H1 + N32;             // N*CAP ushorts
    unsigned* ovf    = (unsigned*)(ebuf + N_NODES * CAP);
    unsigned char* revb = (unsigned char*)(ovf + NE);
    unsigned* bbuf   = (unsigned*)(revb + NE);   // NBUCK*BCAP
    unsigned* jbbuf  = bbuf + NBUCK * BCAP;      // NBUCK*JBCAP
    unsigned* ovf2   = jbbuf + NBUCK * JBCAP;    // NE
    unsigned* jovf   = ovf2 + NE;                // NE
    float*    pdot   = (float*)bbuf;             // alias

    // Re-init (ws is poisoned 0xAA before every call)
    size_t zero_bytes = (size_t)(N_NODES + 16 + 2 * NBUCK) * 4;
    hipMemsetAsync(cnt, 0, zero_bytes, stream);

    // Bin both edge sets, then XCD-affine scatter (adj) -> ebuf + cnt
    const int NB_ADJ = (NE + 256 * EPT - 1) / (256 * EPT);
    k_bin<<<2 * NB_ADJ, 256, 0, stream>>>(adj_row, adj_col, j_idx,
                                          bcnt, bbuf, ovf2, ovfcnts + 4,
                                          jbcnt, jbbuf, jovf, ovfcnts + 8);
    k_scatter2<<<8 * LBUCK * (BCAP / PBCH) + 8, 256, 0, stream>>>(bbuf, bcnt, cnt, ebuf,
                                                                  ovf, ovfcnts, ovf2, ovfcnts + 4);

    // Fused: gemm layer1 + dinv + reverse-edge scan
    const int GB = N_NODES / 32, DB = (N_NODES + 255) / 256, RB = NE * 8 / 256;
    k_fused1<<<GB + DB + RB, 256, 0, stream>>>(features, W1, A0, A1, cnt, dinv, j_idx, revb);

    // Layer 1 aggregate (overflow handled inline)
    k_aggf3<true, false><<<(N_NODES / 2 * 64 + 255) / 256, 256, 0, stream>>>(
        (const uint2*)A0, (const uint2*)A1, (uint2*)B16, nullptr, nullptr,
        dinv, cnt, ebuf, b1, ovf, ovfcnts);

    // Layer 2
    k_gemm2<<<N_NODES / 32, 256, 0, stream>>>(B16, W2, A0, A1);
    k_aggf3<false, true><<<(N_NODES / 2 * 64 + 255) / 256, 256, 0, stream>>>(
        (const uint2*)A0, (const uint2*)A1, nullptr, (uint2*)H0, (uint2*)H1,
        dinv, cnt, ebuf, b2, ovf, ovfcnts);

    // Edge scores: half-0 partial dots, then half-1 + symmetrize (atomic-free)
    float* outS = out + 2 * NE;
    k_dot0<<<NE * 8 / 256, 256, 0, stream>>>((const uint4*)H0, j_idx, pdot);
    k_edgesym2<<<NE * 8 / 256, 256, 0, stream>>>((const uint4*)H1, pdot, s_d, j_idx, revb, outS);

    // Binned in-edge accumulation + dinv2, then final normalize
    k_jagg<<<NBUCK, 1024, 0, stream>>>(jbbuf, jbcnt, outS, dinv2, jovf, ovfcnts + 8, j_idx);
    k_norm<<<2 * NE / 256, 256, 0, stream>>>(outS, dinv2, j_idx, out);
}

// Round 11
// 271.637 us; speedup vs baseline: 1.2132x; 1.0784x over previous
//
#include <hip/hip_runtime.h>

// Problem constants (match reference)
#define N_NODES 40000
#define ISIZE   64
#define KNN     24
#define NE      (N_NODES * KNN)      // 960000 edges (= E_ADJ as well)
#define OMEGA   0.9f
#define CAP     64                   // per-node bucket capacity (max deg ~46)
#define NBUCK   80                   // buckets of 512 nodes (idx>>9)
#define LBUCK   10                   // buckets per XCD (NBUCK/8)
#define BCAP    16384                // adj edges per bucket capacity (mean 12288)
#define JBCAP   16384                // learner edges per bucket capacity
#define EPT     8                    // edges per thread in bin pass
#define PBCH    512                  // edges per block in k_scatter2

// ---- bf16 helpers (storage-only precision; all math in fp32) -------------
__device__ __forceinline__ float bf2f(unsigned short s) {
    return __uint_as_float(((unsigned)s) << 16);
}
__device__ __forceinline__ unsigned short f2bf(float f) {  // round-nearest-even
    unsigned u = __float_as_uint(f);
    u += 0x7fffu + ((u >> 16) & 1u);
    return (unsigned short)(u >> 16);
}
__device__ __forceinline__ float bflo(unsigned u) { return __uint_as_float(u << 16); }
__device__ __forceinline__ float bfhi(unsigned u) { return __uint_as_float(u & 0xffff0000u); }
__device__ __forceinline__ unsigned pack2(float lo, float hi) {
    return (unsigned)f2bf(lo) | ((unsigned)f2bf(hi) << 16);
}

// ---- mega front end: gemm layer1 | bin both edge sets | reverse scan -----
// All three are mutually independent; one launch saves 2 dispatch gaps.
__global__ void k_mega1(const float* __restrict__ X, const float* __restrict__ W,
                        unsigned short* __restrict__ Y0, unsigned short* __restrict__ Y1,
                        const int* __restrict__ row, const int* __restrict__ col,
                        const int* __restrict__ j_idx,
                        int* __restrict__ bcnt, unsigned* __restrict__ bbuf,
                        unsigned* __restrict__ ovf2, int* __restrict__ ovf2_cnt,
                        int* __restrict__ jbcnt, unsigned* __restrict__ jbbuf,
                        unsigned* __restrict__ jovf, int* __restrict__ jovf_cnt,
                        unsigned char* __restrict__ revb) {
    __shared__ float sW[64 * 64];    // gemm: W tile | bin: lcnt/lbase overlay
    __shared__ float sX[32 * 64];
    const int GB  = N_NODES / 32;                          // 1250 gemm blocks
    const int NBA = (NE + 256 * EPT - 1) / (256 * EPT);    // 469 bin blocks per set
    int bx = blockIdx.x;
    int tid = threadIdx.x;
    if (bx < GB) {
        // ---- GEMM layer 1: rows bx*32.., split-half bf16 output ----
        int row0 = bx * 32;
        for (int t = tid; t < 1024; t += 256)
            ((float4*)sW)[t] = ((const float4*)W)[t];
        for (int t = tid; t < 512; t += 256)
            ((float4*)sX)[t] = ((const float4*)(X + row0 * 64))[t];
        __syncthreads();
        int cc = tid & 63;
        int rl = tid >> 6;
        for (int r = rl; r < 32; r += 4) {
            float acc = 0.0f;
#pragma unroll
            for (int kk = 0; kk < 64; kk++) acc += sX[r * 64 + kk] * sW[kk * 64 + cc];
            if (cc < 32) Y0[(row0 + r) * 32 + cc]      = f2bf(acc);
            else         Y1[(row0 + r) * 32 + cc - 32] = f2bf(acc);
        }
    } else if (bx < GB + 2 * NBA) {
        // ---- bin edges: adj by col (r<<16|c), learner by j ((j&511)<<20|e)
        int* lcnt  = (int*)sW;
        int* lbase = lcnt + NBUCK;
        int blk = bx - GB;
        bool adj = blk < NBA;
        if (!adj) blk -= NBA;
        for (int b = tid; b < NBUCK; b += 256) lcnt[b] = 0;
        __syncthreads();
        int e0 = blk * (256 * EPT);
        int myslot[EPT]; int myb[EPT]; unsigned myp[EPT];
        for (int k = 0; k < EPT; k++) {
            int e = e0 + k * 256 + tid;
            if (e < NE) {
                int b; unsigned p;
                if (adj) { int r = row[e], c = col[e]; b = c >> 9; p = ((unsigned)r << 16) | (unsigned)c; }
                else     { int j = j_idx[e];           b = j >> 9; p = ((unsigned)(j & 511) << 20) | (unsigned)e; }
                myb[k] = b; myp[k] = p;
                myslot[k] = atomicAdd(&lcnt[b], 1);
            } else myb[k] = -1;
        }
        __syncthreads();
        int* gcnt = adj ? bcnt : jbcnt;
        for (int b = tid; b < NBUCK; b += 256)
            lbase[b] = (lcnt[b] > 0) ? atomicAdd(&gcnt[b], lcnt[b]) : 0;
        __syncthreads();
        unsigned* gbuf = adj ? bbuf : jbbuf;
        unsigned* govf = adj ? ovf2 : jovf;
        int* gocnt = adj ? ovf2_cnt : jovf_cnt;
        for (int k = 0; k < EPT; k++) {
            if (myb[k] < 0) continue;
            int pos = lbase[myb[k]] + myslot[k];
            if (pos < BCAP) gbuf[myb[k] * BCAP + pos] = myp[k];
            else { int p = atomicAdd(gocnt, 1); govf[p] = myp[k]; }
        }
    } else {
        // ---- reverse-edge match: scan j's 24-edge slice (j_idx L2-resident)
        int t = (bx - GB - 2 * NBA) * 256 + tid;   // NE*8 threads
        int e = t >> 3;
        int q = t & 7;
        int i = e / KNN;
        int j = j_idx[e];
        const int* jj = j_idx + j * KNN;
        int rt = 255;
        if (jj[q] == i) rt = q;
        if (jj[8 + q] == i) rt = min(rt, 8 + q);
        if (jj[16 + q] == i) rt = min(rt, 16 + q);
#pragma unroll
        for (int m = 1; m < 8; m <<= 1) rt = min(rt, __shfl_xor(rt, m));
        if (q == 0) revb[e] = (unsigned char)rt;
    }
}

// ---- XCD-affine scatter into ebuf (+ adj-bin-overflow tail blocks) -------
__global__ void k_scatter2(const unsigned* __restrict__ bbuf, const int* __restrict__ bcnt,
                           int* __restrict__ cnt, unsigned short* __restrict__ ebuf,
                           unsigned* __restrict__ ovf, int* __restrict__ ovf_cnt,
                           const unsigned* __restrict__ ovf2, const int* __restrict__ ovf2_cnt) {
    const int MAIN = 8 * LBUCK * (BCAP / PBCH);   // 2560
    if ((int)blockIdx.x >= MAIN) {                // adj bin-overflow fallback (normally 0)
        int m = ovf2_cnt[0];
        for (int t = (blockIdx.x - MAIN) * 256 + threadIdx.x; t < m; t += 8 * 256) {
            unsigned p = ovf2[t];
            int c = (int)(p & 0xffffu), r = (int)(p >> 16);
            int slot = atomicAdd(&cnt[c], 1);
            if (slot < CAP) ebuf[c * CAP + slot] = (unsigned short)r;
            else { int q = atomicAdd(ovf_cnt, 1); ovf[q] = p; }
        }
        return;
    }
    int xcd = blockIdx.x & 7;
    int t   = blockIdx.x >> 3;
    int lb  = t % LBUCK;
    int chunk = t / LBUCK;
    int b = xcd + 8 * lb;                  // bucket; b%8==xcd for L2 locality
    int n = min(bcnt[b], BCAP);
    int start = chunk * PBCH;
    if (start >= n) return;
    int end = min(start + PBCH, n);
    for (int idx = start + threadIdx.x; idx < end; idx += 256) {
        unsigned p = bbuf[b * BCAP + idx];
        int c = (int)(p & 0xffffu), r = (int)(p >> 16);
        int slot = atomicAdd(&cnt[c], 1);
        if (slot < CAP) ebuf[c * CAP + slot] = (unsigned short)r;
        else { int q = atomicAdd(ovf_cnt, 1); ovf[q] = p; }
    }
}

// ---- Y = X @ W (layer 2), bf16 split-half output -------------------------
__global__ void k_gemm2(const unsigned short* __restrict__ X, const float* __restrict__ W,
                        unsigned short* __restrict__ Y0, unsigned short* __restrict__ Y1) {
    __shared__ float sW[64 * 64];
    __shared__ float sX[32 * 64];
    int row0 = blockIdx.x * 32;
    for (int t = threadIdx.x; t < 1024; t += 256)
        ((float4*)sW)[t] = ((const float4*)W)[t];
    for (int t = threadIdx.x; t < 512; t += 256) {
        uint2 u = ((const uint2*)(X + row0 * 64))[t];
        ((float4*)sX)[t] = make_float4(bflo(u.x), bfhi(u.x), bflo(u.y), bfhi(u.y));
    }
    __syncthreads();
    int col = threadIdx.x & 63;
    int rl  = threadIdx.x >> 6;
    for (int r = rl; r < 32; r += 4) {
        float acc = 0.0f;
#pragma unroll
        for (int kk = 0; kk < 64; kk++) acc += sX[r * 64 + kk] * sW[kk * 64 + col];
        if (col < 32) Y0[(row0 + r) * 32 + col]      = f2bf(acc);
        else          Y1[(row0 + r) * 32 + col - 32] = f2bf(acc);
    }
}

// ---- pull aggregation: 2 nodes/wave, uint4 dual-half gathers, inline dinv
// 32-lane half per node: 8 row-groups (g) x 4 uint4 quarters (f).
// Each iteration gathers 8 rows x both halves (2x16B loads/lane); np=3 @deg24.
// dinv computed inline from cnt (same gather cost as a dinv load).
template<bool RELU, bool NORM>
__global__ void k_aggf4(const uint4* __restrict__ X0q, const uint4* __restrict__ X1q,
                        uint4* __restrict__ outFq,   // layer1: full rows, N*8 uint4
                        uint4* __restrict__ O0q, uint4* __restrict__ O1q, // layer2 halves, N*4
                        const int* __restrict__ cnt,
                        const unsigned short* __restrict__ ebuf, const float* __restrict__ bias,
                        const unsigned* __restrict__ ovf, const int* __restrict__ ovf_cnt) {
    int w = (blockIdx.x * 256 + threadIdx.x) >> 6;   // wave id, 2 nodes/wave
    int lane = threadIdx.x & 63;
    int half = lane >> 5, sl = lane & 31;
    int n = w * 2 + half;
    if (n >= N_NODES) return;
    int deg = cnt[n];
    int bucketed = min(deg, CAP);
    int nb0 = min(bucketed, 32);
    int nb1 = bucketed - nb0;

    int   r0v = 0, r1v = 0;
    float d0v = 0.0f, d1v = 0.0f;                    // 0 coef for idle entries
    if (sl < nb0) { r0v = (int)ebuf[n * CAP + sl];      d0v = rsqrtf(1.0f + (float)cnt[r0v]); }
    if (sl < nb1) { r1v = (int)ebuf[n * CAP + 32 + sl]; d1v = rsqrtf(1.0f + (float)cnt[r1v]); }

    int g = sl >> 2;          // row subgroup 0..7
    int f = sl & 3;           // uint4 quarter: features 8f..8f+7 of each half

    float a[16];
#pragma unroll
    for (int k = 0; k < 16; k++) a[k] = 0.f;

    int np0 = (nb0 + 7) >> 3;
    int np1 = (nb1 + 7) >> 3;

#pragma unroll 4
    for (int d = 0; d < np0; d++) {
        int   q = 8 * d + g;
        int   r = __shfl(r0v, q, 32);
        float c = __shfl(d0v, q, 32);
        uint4 u0 = X0q[r * 4 + f];
        uint4 u1 = X1q[r * 4 + f];
        a[0]  += c * bflo(u0.x); a[1]  += c * bfhi(u0.x);
        a[2]  += c * bflo(u0.y); a[3]  += c * bfhi(u0.y);
        a[4]  += c * bflo(u0.z); a[5]  += c * bfhi(u0.z);
        a[6]  += c * bflo(u0.w); a[7]  += c * bfhi(u0.w);
        a[8]  += c * bflo(u1.x); a[9]  += c * bfhi(u1.x);
        a[10] += c * bflo(u1.y); a[11] += c * bfhi(u1.y);
        a[12] += c * bflo(u1.z); a[13] += c * bfhi(u1.z);
        a[14] += c * bflo(u1.w); a[15] += c * bfhi(u1.w);
    }
#pragma unroll 4
    for (int d = 0; d < np1; d++) {
        int   q = 8 * d + g;
        int   r = __shfl(r1v, q, 32);
        float c = __shfl(d1v, q, 32);
        uint4 u0 = X0q[r * 4 + f];
        uint4 u1 = X1q[r * 4 + f];
        a[0]  += c * bflo(u0.x); a[1]  += c * bfhi(u0.x);
        a[2]  += c * bflo(u0.y); a[3]  += c * bfhi(u0.y);
        a[4]  += c * bflo(u0.z); a[5]  += c * bfhi(u0.z);
        a[6]  += c * bflo(u0.w); a[7]  += c * bfhi(u0.w);
        a[8]  += c * bflo(u1.x); a[9]  += c * bfhi(u1.x);
        a[10] += c * bflo(u1.y); a[11] += c * bfhi(u1.y);
        a[12] += c * bflo(u1.z); a[13] += c * bfhi(u1.z);
        a[14] += c * bflo(u1.w); a[15] += c * bfhi(u1.w);
    }

    // CAP-overflow edges (normally none): g==0 lanes (f=0..3) scan ovf list
    if (deg > CAP) {
        int m = ovf_cnt[0];
        for (int k2 = 0; k2 < m; k2++) {
            unsigned p = ovf[k2];
            if ((int)(p & 0xffffu) == n && g == 0) {
                int r = (int)(p >> 16);
                float c = rsqrtf(1.0f + (float)cnt[r]);
                uint4 u0 = X0q[r * 4 + f], u1 = X1q[r * 4 + f];
                a[0]  += c * bflo(u0.x); a[1]  += c * bfhi(u0.x);
                a[2]  += c * bflo(u0.y); a[3]  += c * bfhi(u0.y);
                a[4]  += c * bflo(u0.z); a[5]  += c * bfhi(u0.z);
                a[6]  += c * bflo(u0.w); a[7]  += c * bfhi(u0.w);
                a[8]  += c * bflo(u1.x); a[9]  += c * bfhi(u1.x);
                a[10] += c * bflo(u1.y); a[11] += c * bfhi(u1.y);
                a[12] += c * bflo(u1.z); a[13] += c * bfhi(u1.z);
                a[14] += c * bflo(u1.w); a[15] += c * bfhi(u1.w);
            }
        }
    }

    // merge the 8 row-subgroups
#pragma unroll
    for (int k = 0; k < 16; k++) {
        a[k] += __shfl_xor(a[k], 4, 32);
        a[k] += __shfl_xor(a[k], 8, 32);
        a[k] += __shfl_xor(a[k], 16, 32);
    }

    float di = rsqrtf(1.0f + (float)deg);
    float dd = di * di;
    uint4 s0 = X0q[n * 4 + f], s1 = X1q[n * 4 + f];
    float4 bA0 = ((const float4*)bias)[2 * f];
    float4 bA1 = ((const float4*)bias)[2 * f + 1];
    float4 bB0 = ((const float4*)(bias + 32))[2 * f];
    float4 bB1 = ((const float4*)(bias + 32))[2 * f + 1];
    float v[16];
    v[0]  = di * a[0]  + dd * bflo(s0.x) + bA0.x;
    v[1]  = di * a[1]  + dd * bfhi(s0.x) + bA0.y;
    v[2]  = di * a[2]  + dd * bflo(s0.y) + bA0.z;
    v[3]  = di * a[3]  + dd * bfhi(s0.y) + bA0.w;
    v[4]  = di * a[4]  + dd * bflo(s0.z) + bA1.x;
    v[5]  = di * a[5]  + dd * bfhi(s0.z) + bA1.y;
    v[6]  = di * a[6]  + dd * bflo(s0.w) + bA1.z;
    v[7]  = di * a[7]  + dd * bfhi(s0.w) + bA1.w;
    v[8]  = di * a[8]  + dd * bflo(s1.x) + bB0.x;
    v[9]  = di * a[9]  + dd * bfhi(s1.x) + bB0.y;
    v[10] = di * a[10] + dd * bflo(s1.y) + bB0.z;
    v[11] = di * a[11] + dd * bfhi(s1.y) + bB0.w;
    v[12] = di * a[12] + dd * bflo(s1.z) + bB1.x;
    v[13] = di * a[13] + dd * bfhi(s1.z) + bB1.y;
    v[14] = di * a[14] + dd * bflo(s1.w) + bB1.z;
    v[15] = di * a[15] + dd * bfhi(s1.w) + bB1.w;
    if (RELU) {
#pragma unroll
        for (int k = 0; k < 16; k++) v[k] = fmaxf(v[k], 0.f);
    }
    if (NORM) {
        float s = 0.f;
#pragma unroll
        for (int k = 0; k < 16; k++) s += v[k] * v[k];
        s += __shfl_xor(s, 1, 32);
        s += __shfl_xor(s, 2, 32);
        float inv = 1.0f / fmaxf(sqrtf(s), 1e-12f);
#pragma unroll
        for (int k = 0; k < 16; k++) v[k] *= inv;
        if (g == 0) {
            O0q[n * 4 + f] = make_uint4(pack2(v[0], v[1]),  pack2(v[2], v[3]),
                                        pack2(v[4], v[5]),  pack2(v[6], v[7]));
            O1q[n * 4 + f] = make_uint4(pack2(v[8], v[9]),  pack2(v[10], v[11]),
                                        pack2(v[12], v[13]), pack2(v[14], v[15]));
        }
    } else {
        if (g == 0) {
            outFq[n * 8 + f]     = make_uint4(pack2(v[0], v[1]),  pack2(v[2], v[3]),
                                              pack2(v[4], v[5]),  pack2(v[6], v[7]));
            outFq[n * 8 + 4 + f] = make_uint4(pack2(v[8], v[9]),  pack2(v[10], v[11]),
                                              pack2(v[12], v[13]), pack2(v[14], v[15]));
        }
    }
}

// ---- fused edge dot (both halves) + finalize + symmetrize (NO atomics) ---
// 8 lanes/edge: lanes 0-3 fetch i's quarters, 4-7 fetch j's; each lane loads
// H0 AND H1 quarters (2 independent gathers -> 2x MLP); shfl_xor(4) partners.
__global__ void k_dotsym(const uint4* __restrict__ H0q, const uint4* __restrict__ H1q,
                         const float* __restrict__ s_d, const int* __restrict__ j_idx,
                         const unsigned char* __restrict__ revb,
                         float* __restrict__ outS) {   // d_out + 2E, holds vals_s [2E]
    int t = blockIdx.x * 256 + threadIdx.x;   // NE*8 threads
    int e = t >> 3;
    int q = t & 7;
    int g = q >> 2, f = q & 3;
    int i = e / KNN;
    int j = j_idx[e];
    int node = g ? j : i;
    uint4 u0 = H0q[node * 4 + f];
    uint4 u1 = H1q[node * 4 + f];
    uint4 p0, p1;
    p0.x = __shfl_xor(u0.x, 4); p0.y = __shfl_xor(u0.y, 4);
    p0.z = __shfl_xor(u0.z, 4); p0.w = __shfl_xor(u0.w, 4);
    p1.x = __shfl_xor(u1.x, 4); p1.y = __shfl_xor(u1.y, 4);
    p1.z = __shfl_xor(u1.z, 4); p1.w = __shfl_xor(u1.w, 4);
    float s = bflo(u0.x) * bflo(p0.x) + bfhi(u0.x) * bfhi(p0.x)
            + bflo(u0.y) * bflo(p0.y) + bfhi(u0.y) * bfhi(p0.y)
            + bflo(u0.z) * bflo(p0.z) + bfhi(u0.z) * bfhi(p0.z)
            + bflo(u0.w) * bflo(p0.w) + bfhi(u0.w) * bfhi(p0.w)
            + bflo(u1.x) * bflo(p1.x) + bfhi(u1.x) * bfhi(p1.x)
            + bflo(u1.y) * bflo(p1.y) + bfhi(u1.y) * bfhi(p1.y)
            + bflo(u1.z) * bflo(p1.z) + bfhi(u1.z) * bfhi(p1.z)
            + bflo(u1.w) * bflo(p1.w) + bfhi(u1.w) * bfhi(p1.w);
    s += __shfl_xor(s, 1);
    s += __shfl_xor(s, 2);
    if (q == 0) {
        float base = OMEGA * fmaxf(s, 0.0f);
        int rt = revb[e];
        float vv, v2;
        if (rt != 255) {                     // reverse edge exists (rare)
            int rev = j * KNN + rt;
            vv = base + 0.5f * (1.0f - OMEGA) * (s_d[e] + s_d[rev]);
            v2 = 0.0f;
        } else {
            vv = base + (1.0f - OMEGA) * s_d[e];
            v2 = vv;
        }
        outS[e] = vv;
        outS[NE + e] = v2;
    }
}

// ---- binned in-edge accumulation + fused dinv2 ---------------------------
__global__ void k_jagg(const unsigned* __restrict__ jbbuf, const int* __restrict__ jbcnt,
                       const float* __restrict__ outS, float* __restrict__ dinv2,
                       const unsigned* __restrict__ jovf, const int* __restrict__ jovf_cnt,
                       const int* __restrict__ j_idx) {
    __shared__ float ld[512];
    int b = blockIdx.x;
    int tid = threadIdx.x;                   // 1024 threads
    if (tid < 512) ld[tid] = 0.0f;
    __syncthreads();
    const float* outSv2 = outS + NE;
    int n = min(jbcnt[b], JBCAP);
    for (int idx = tid; idx < n; idx += 1024) {
        unsigned p = jbbuf[b * JBCAP + idx];
        atomicAdd(&ld[p >> 20], outSv2[p & 0xFFFFFu]);
    }
    int m = jovf_cnt[0];                     // learner bin overflow (normally 0)
    for (int t2 = tid; t2 < m; t2 += 1024) {
        int e = (int)(jovf[t2] & 0xFFFFFu);
        int j = j_idx[e];
        if ((j >> 9) == b) atomicAdd(&ld[j & 511], outSv2[e]);
    }
    __syncthreads();
    if (tid < 512) {
        int node = b * 512 + tid;
        if (node < N_NODES) {
            float d = ld[tid];
            const float* pp = outS + node * KNN;
#pragma unroll
            for (int qq = 0; qq < KNN; qq++) d += pp[qq];
            dinv2[node] = (d > 0.0f) ? rsqrtf(fmaxf(d, 1e-12f)) : 0.0f;
        }
    }
}

// ---- final normalization: vals_norm = dinv2[r] * vals_s * dinv2[c] -------
__global__ void k_norm(const float* __restrict__ outS, const float* __restrict__ dinv2,
                       const int* __restrict__ j_idx, float* __restrict__ out) {
    int t = blockIdx.x * 256 + threadIdx.x;   // 2*NE threads
    int r, c;
    if (t < NE) { r = t / KNN; c = j_idx[t]; }
    else        { int e = t - NE; r = j_idx[e]; c = e / KNN; }
    out[t] = dinv2[r] * outS[t] * dinv2[c];
}

extern "C" void kernel_launch(void* const* d_in, const int* in_sizes, int n_in,
                              void* d_out, int out_size, void* d_ws, size_t ws_size,
                              hipStream_t stream) {
    const float* features = (const float*)d_in[0];
    const float* W1       = (const float*)d_in[1];
    const float* b1       = (const float*)d_in[2];
    const float* W2       = (const float*)d_in[3];
    const float* b2       = (const float*)d_in[4];
    const float* s_d      = (const float*)d_in[5];
    const int*   adj_row  = (const int*)d_in[6];
    const int*   adj_col  = (const int*)d_in[7];
    const int*   j_idx    = (const int*)d_in[9];
    float* out = (float*)d_out;

    const int N64 = N_NODES * 64;
    const int N32 = N_NODES * 32;
    // Workspace layout (zero region first, all offsets 16B-aligned):
    // [cnt N][ovfcnts 16][bcnt 80][jbcnt 80]  <- memset 0
    // [dinv2 N][A0 N32 us][A1 N32 us][B16 N64 us][H0 N32 us][H1 N32 us]
    // [ebuf N*CAP us][ovf NE u][revb NE uc][bbuf][jbbuf][ovf2 NE u][jovf NE u]
    int*   cnt     = (int*)d_ws;
    int*   ovfcnts = cnt + N_NODES;          // [0]=CAP ovf, [4]=adj bin ovf, [8]=learner bin ovf
    int*   bcnt    = ovfcnts + 16;
    int*   jbcnt   = bcnt + NBUCK;
    float* dinv2   = (float*)(jbcnt + NBUCK);
    unsigned short* A0  = (unsigned short*)(dinv2 + N_NODES);
    unsigned short* A1  = A0 + N32;
    unsigned short* B16 = A1 + N32;
    unsigned short* H0  = B16 + N64;
    unsigned short* H1  = H0 + N32;
    unsigned short* ebuf = H1 + N32;             // N*CAP ushorts
    unsigned* ovf    = (unsigned*)(ebuf + N_NODES * CAP);
    unsigned char* revb = (unsigned char*)(ovf + NE);
    unsigned* bbuf   = (unsigned*)(revb + NE);   // NBUCK*BCAP
    unsigned* jbbuf  = bbuf + NBUCK * BCAP;      // NBUCK*JBCAP
    unsigned* ovf2   = jbbuf + NBUCK * JBCAP;    // NE
    unsigned* jovf   = ovf2 + NE;                // NE

    // Re-init (ws is poisoned 0xAA before every call)
    size_t zero_bytes = (size_t)(N_NODES + 16 + 2 * NBUCK) * 4;
    hipMemsetAsync(cnt, 0, zero_bytes, stream);

    // Mega front end: gemm1 + bin(both sets) + reverse-edge scan
    const int GB = N_NODES / 32;                          // 1250
    const int NBA = (NE + 256 * EPT - 1) / (256 * EPT);   // 469
    const int RB = NE * 8 / 256;                          // 30000
    k_mega1<<<GB + 2 * NBA + RB, 256, 0, stream>>>(
        features, W1, A0, A1, adj_row, adj_col, j_idx,
        bcnt, bbuf, ovf2, ovfcnts + 4, jbcnt, jbbuf, jovf, ovfcnts + 8, revb);

    // XCD-affine scatter (adj) -> ebuf + cnt
    k_scatter2<<<8 * LBUCK * (BCAP / PBCH) + 8, 256, 0, stream>>>(
        bbuf, bcnt, cnt, ebuf, ovf, ovfcnts, ovf2, ovfcnts + 4);

    // Layer 1 aggregate (dinv inline from cnt; overflow inline)
    k_aggf4<true, false><<<(N_NODES / 2 * 64 + 255) / 256, 256, 0, stream>>>(
        (const uint4*)A0, (const uint4*)A1, (uint4*)B16, nullptr, nullptr,
        cnt, ebuf, b1, ovf, ovfcnts);

    // Layer 2
    k_gemm2<<<N_NODES / 32, 256, 0, stream>>>(B16, W2, A0, A1);
    k_aggf4<false, true><<<(N_NODES / 2 * 64 + 255) / 256, 256, 0, stream>>>(
        (const uint4*)A0, (const uint4*)A1, nullptr, (uint4*)H0, (uint4*)H1,
        cnt, ebuf, b2, ovf, ovfcnts);

    // Fused edge scores + symmetrize (atomic-free, dual-half MLP)
    float* outS = out + 2 * NE;
    k_dotsym<<<NE * 8 / 256, 256, 0, stream>>>(
        (const uint4*)H0, (const uint4*)H1, s_d, j_idx, revb, outS);

    // Binned in-edge accumulation + dinv2, then final normalize
    k_jagg<<<NBUCK, 1024, 0, stream>>>(jbbuf, jbcnt, outS, dinv2, jovf, ovfcnts + 8, j_idx);
    k_norm<<<2 * NE / 256, 256, 0, stream>>>(outS, dinv2, j_idx, out);
}

// Round 12
// 252.036 us; speedup vs baseline: 1.3075x; 1.0778x over previous
//
#include <hip/hip_runtime.h>

// Problem constants (match reference)
#define N_NODES 40000
#define ISIZE   64
#define KNN     24
#define NE      (N_NODES * KNN)      // 960000 edges (= E_ADJ as well)
#define OMEGA   0.9f
#define CAP     64                   // per-node bucket capacity (max deg ~46)
#define NBUCK   80                   // buckets of 512 nodes (idx>>9)
#define BCAP    16384                // adj edges per bucket capacity (mean 12288)
#define JBCAP   16384                // learner edges per bucket capacity
#define EPT     8                    // edges per thread in bin pass

// ---- bf16 helpers (storage-only precision; all math in fp32) -------------
__device__ __forceinline__ float bf2f(unsigned short s) {
    return __uint_as_float(((unsigned)s) << 16);
}
__device__ __forceinline__ unsigned short f2bf(float f) {  // round-nearest-even
    unsigned u = __float_as_uint(f);
    u += 0x7fffu + ((u >> 16) & 1u);
    return (unsigned short)(u >> 16);
}
__device__ __forceinline__ float bflo(unsigned u) { return __uint_as_float(u << 16); }
__device__ __forceinline__ float bfhi(unsigned u) { return __uint_as_float(u & 0xffff0000u); }
__device__ __forceinline__ unsigned pack2(float lo, float hi) {
    return (unsigned)f2bf(lo) | ((unsigned)f2bf(hi) << 16);
}

// ---- mega front end: gemm layer1 | bin both edge sets | reverse scan -----
__global__ void k_mega1(const float* __restrict__ X, const float* __restrict__ W,
                        unsigned short* __restrict__ Y0, unsigned short* __restrict__ Y1,
                        const int* __restrict__ row, const int* __restrict__ col,
                        const int* __restrict__ j_idx,
                        int* __restrict__ bcnt, unsigned* __restrict__ bbuf,
                        unsigned* __restrict__ ovf2, int* __restrict__ ovf2_cnt,
                        int* __restrict__ jbcnt, unsigned* __restrict__ jbbuf,
                        unsigned* __restrict__ jovf, int* __restrict__ jovf_cnt,
                        unsigned char* __restrict__ revb) {
    __shared__ float sW[64 * 64];    // gemm: W tile | bin: lcnt/lbase overlay
    __shared__ float sX[32 * 64];
    const int GB  = N_NODES / 32;                          // 1250 gemm blocks
    const int NBA = (NE + 256 * EPT - 1) / (256 * EPT);    // 469 bin blocks per set
    int bx = blockIdx.x;
    int tid = threadIdx.x;
    if (bx < GB) {
        // ---- GEMM layer 1: rows bx*32.., split-half bf16 output ----
        int row0 = bx * 32;
        for (int t = tid; t < 1024; t += 256)
            ((float4*)sW)[t] = ((const float4*)W)[t];
        for (int t = tid; t < 512; t += 256)
            ((float4*)sX)[t] = ((const float4*)(X + row0 * 64))[t];
        __syncthreads();
        int cc = tid & 63;
        int rl = tid >> 6;
        for (int r = rl; r < 32; r += 4) {
            float acc = 0.0f;
#pragma unroll
            for (int kk = 0; kk < 64; kk++) acc += sX[r * 64 + kk] * sW[kk * 64 + cc];
            if (cc < 32) Y0[(row0 + r) * 32 + cc]      = f2bf(acc);
            else         Y1[(row0 + r) * 32 + cc - 32] = f2bf(acc);
        }
    } else if (bx < GB + 2 * NBA) {
        // ---- bin edges: adj by col (r<<16|c), learner by j ((j&511)<<20|e)
        int* lcnt  = (int*)sW;
        int* lbase = lcnt + NBUCK;
        int blk = bx - GB;
        bool adj = blk < NBA;
        if (!adj) blk -= NBA;
        for (int b = tid; b < NBUCK; b += 256) lcnt[b] = 0;
        __syncthreads();
        int e0 = blk * (256 * EPT);
        int myslot[EPT]; int myb[EPT]; unsigned myp[EPT];
        for (int k = 0; k < EPT; k++) {
            int e = e0 + k * 256 + tid;
            if (e < NE) {
                int b; unsigned p;
                if (adj) { int r = row[e], c = col[e]; b = c >> 9; p = ((unsigned)r << 16) | (unsigned)c; }
                else     { int j = j_idx[e];           b = j >> 9; p = ((unsigned)(j & 511) << 20) | (unsigned)e; }
                myb[k] = b; myp[k] = p;
                myslot[k] = atomicAdd(&lcnt[b], 1);
            } else myb[k] = -1;
        }
        __syncthreads();
        int* gcnt = adj ? bcnt : jbcnt;
        for (int b = tid; b < NBUCK; b += 256)
            lbase[b] = (lcnt[b] > 0) ? atomicAdd(&gcnt[b], lcnt[b]) : 0;
        __syncthreads();
        unsigned* gbuf = adj ? bbuf : jbbuf;
        unsigned* govf = adj ? ovf2 : jovf;
        int* gocnt = adj ? ovf2_cnt : jovf_cnt;
        for (int k = 0; k < EPT; k++) {
            if (myb[k] < 0) continue;
            int pos = lbase[myb[k]] + myslot[k];
            if (pos < BCAP) gbuf[myb[k] * BCAP + pos] = myp[k];
            else { int p = atomicAdd(gocnt, 1); govf[p] = myp[k]; }
        }
    } else {
        // ---- reverse-edge match: 1 thread/edge, 6 x uint4 over j's slice -
        int e = (bx - GB - 2 * NBA) * 256 + tid;   // NE threads
        int i = e / KNN;
        int j = j_idx[e];
        const uint4* jj4 = (const uint4*)(j_idx + j * KNN);  // 96B rows: 16B-aligned
        int rt = 255;
#pragma unroll
        for (int k = 5; k >= 0; k--) {             // descending so min index wins
            uint4 u = jj4[k];
            if ((int)u.w == i) rt = 4 * k + 3;
            if ((int)u.z == i) rt = 4 * k + 2;
            if ((int)u.y == i) rt = 4 * k + 1;
            if ((int)u.x == i) rt = 4 * k + 0;
        }
        revb[e] = (unsigned char)rt;
    }
}

// ---- per-bucket scatter: LDS slot assignment, NO global atomics ----------
// Block b exclusively owns nodes [b*512,(b+1)*512): slots via LDS atomics,
// ebuf plain stores into the bucket's private 64KB window, cnt plain store.
__global__ void k_scatter3(const unsigned* __restrict__ bbuf, const int* __restrict__ bcnt,
                           int* __restrict__ cnt, unsigned short* __restrict__ ebuf,
                           unsigned* __restrict__ ovf, int* __restrict__ ovf_cnt,
                           const unsigned* __restrict__ ovf2, const int* __restrict__ ovf2_cnt) {
    __shared__ int lcnt2[512];
    int b = blockIdx.x;
    int tid = threadIdx.x;                   // 1024 threads
    if (tid < 512) lcnt2[tid] = 0;
    __syncthreads();
    int n = min(bcnt[b], BCAP);
    for (int idx = tid; idx < n; idx += 1024) {
        unsigned p = bbuf[b * BCAP + idx];
        int c = (int)(p & 0xffffu), r = (int)(p >> 16);
        int slot = atomicAdd(&lcnt2[c & 511], 1);
        if (slot < CAP) ebuf[c * CAP + slot] = (unsigned short)r;
        else { int q = atomicAdd(ovf_cnt, 1); ovf[q] = p; }
    }
    int m = ovf2_cnt[0];                     // adj bin overflow (normally 0)
    for (int idx = tid; idx < m; idx += 1024) {
        unsigned p = ovf2[idx];
        int c = (int)(p & 0xffffu), r = (int)(p >> 16);
        if ((c >> 9) != b) continue;
        int slot = atomicAdd(&lcnt2[c & 511], 1);
        if (slot < CAP) ebuf[c * CAP + slot] = (unsigned short)r;
        else { int q = atomicAdd(ovf_cnt, 1); ovf[q] = p; }
    }
    __syncthreads();
    if (tid < 512) {
        int node = b * 512 + tid;
        if (node < N_NODES) cnt[node] = lcnt2[tid];   // full degree (incl. >CAP)
    }
}

// ---- Y = X @ W (layer 2), bf16 split-half output -------------------------
__global__ void k_gemm2(const unsigned short* __restrict__ X, const float* __restrict__ W,
                        unsigned short* __restrict__ Y0, unsigned short* __restrict__ Y1) {
    __shared__ float sW[64 * 64];
    __shared__ float sX[32 * 64];
    int row0 = blockIdx.x * 32;
    for (int t = threadIdx.x; t < 1024; t += 256)
        ((float4*)sW)[t] = ((const float4*)W)[t];
    for (int t = threadIdx.x; t < 512; t += 256) {
        uint2 u = ((const uint2*)(X + row0 * 64))[t];
        ((float4*)sX)[t] = make_float4(bflo(u.x), bfhi(u.x), bflo(u.y), bfhi(u.y));
    }
    __syncthreads();
    int col = threadIdx.x & 63;
    int rl  = threadIdx.x >> 6;
    for (int r = rl; r < 32; r += 4) {
        float acc = 0.0f;
#pragma unroll
        for (int kk = 0; kk < 64; kk++) acc += sX[r * 64 + kk] * sW[kk * 64 + col];
        if (col < 32) Y0[(row0 + r) * 32 + col]      = f2bf(acc);
        else          Y1[(row0 + r) * 32 + col - 32] = f2bf(acc);
    }
}

// ---- pull aggregation: 2 nodes/wave, uint4 dual-half gathers, inline dinv
template<bool RELU, bool NORM>
__global__ void k_aggf4(const uint4* __restrict__ X0q, const uint4* __restrict__ X1q,
                        uint4* __restrict__ outFq,   // layer1: full rows, N*8 uint4
                        uint4* __restrict__ O0q, uint4* __restrict__ O1q, // layer2 halves, N*4
                        const int* __restrict__ cnt,
                        const unsigned short* __restrict__ ebuf, const float* __restrict__ bias,
                        const unsigned* __restrict__ ovf, const int* __restrict__ ovf_cnt) {
    int w = (blockIdx.x * 256 + threadIdx.x) >> 6;   // wave id, 2 nodes/wave
    int lane = threadIdx.x & 63;
    int half = lane >> 5, sl = lane & 31;
    int n = w * 2 + half;
    if (n >= N_NODES) return;
    int deg = cnt[n];
    int bucketed = min(deg, CAP);
    int nb0 = min(bucketed, 32);
    int nb1 = bucketed - nb0;

    int   r0v = 0, r1v = 0;
    float d0v = 0.0f, d1v = 0.0f;                    // 0 coef for idle entries
    if (sl < nb0) { r0v = (int)ebuf[n * CAP + sl];      d0v = rsqrtf(1.0f + (float)cnt[r0v]); }
    if (sl < nb1) { r1v = (int)ebuf[n * CAP + 32 + sl]; d1v = rsqrtf(1.0f + (float)cnt[r1v]); }

    int g = sl >> 2;          // row subgroup 0..7
    int f = sl & 3;           // uint4 quarter: features 8f..8f+7 of each half

    float a[16];
#pragma unroll
    for (int k = 0; k < 16; k++) a[k] = 0.f;

    int np0 = (nb0 + 7) >> 3;
    int np1 = (nb1 + 7) >> 3;

#pragma unroll 4
    for (int d = 0; d < np0; d++) {
        int   q = 8 * d + g;
        int   r = __shfl(r0v, q, 32);
        float c = __shfl(d0v, q, 32);
        uint4 u0 = X0q[r * 4 + f];
        uint4 u1 = X1q[r * 4 + f];
        a[0]  += c * bflo(u0.x); a[1]  += c * bfhi(u0.x);
        a[2]  += c * bflo(u0.y); a[3]  += c * bfhi(u0.y);
        a[4]  += c * bflo(u0.z); a[5]  += c * bfhi(u0.z);
        a[6]  += c * bflo(u0.w); a[7]  += c * bfhi(u0.w);
        a[8]  += c * bflo(u1.x); a[9]  += c * bfhi(u1.x);
        a[10] += c * bflo(u1.y); a[11] += c * bfhi(u1.y);
        a[12] += c * bflo(u1.z); a[13] += c * bfhi(u1.z);
        a[14] += c * bflo(u1.w); a[15] += c * bfhi(u1.w);
    }
#pragma unroll 4
    for (int d = 0; d < np1; d++) {
        int   q = 8 * d + g;
        int   r = __shfl(r1v, q, 32);
        float c = __shfl(d1v, q, 32);
        uint4 u0 = X0q[r * 4 + f];
        uint4 u1 = X1q[r * 4 + f];
        a[0]  += c * bflo(u0.x); a[1]  += c * bfhi(u0.x);
        a[2]  += c * bflo(u0.y); a[3]  += c * bfhi(u0.y);
        a[4]  += c * bflo(u0.z); a[5]  += c * bfhi(u0.z);
        a[6]  += c * bflo(u0.w); a[7]  += c * bfhi(u0.w);
        a[8]  += c * bflo(u1.x); a[9]  += c * bfhi(u1.x);
        a[10] += c * bflo(u1.y); a[11] += c * bfhi(u1.y);
        a[12] += c * bflo(u1.z); a[13] += c * bfhi(u1.z);
        a[14] += c * bflo(u1.w); a[15] += c * bfhi(u1.w);
    }

    // CAP-overflow edges (normally none): g==0 lanes (f=0..3) scan ovf list
    if (deg > CAP) {
        int m = ovf_cnt[0];
        for (int k2 = 0; k2 < m; k2++) {
            unsigned p = ovf[k2];
            if ((int)(p & 0xffffu) == n && g == 0) {
                int r = (int)(p >> 16);
                float c = rsqrtf(1.0f + (float)cnt[r]);
                uint4 u0 = X0q[r * 4 + f], u1 = X1q[r * 4 + f];
                a[0]  += c * bflo(u0.x); a[1]  += c * bfhi(u0.x);
                a[2]  += c * bflo(u0.y); a[3]  += c * bfhi(u0.y);
                a[4]  += c * bflo(u0.z); a[5]  += c * bfhi(u0.z);
                a[6]  += c * bflo(u0.w); a[7]  += c * bfhi(u0.w);
                a[8]  += c * bflo(u1.x); a[9]  += c * bfhi(u1.x);
                a[10] += c * bflo(u1.y); a[11] += c * bfhi(u1.y);
                a[12] += c * bflo(u1.z); a[13] += c * bfhi(u1.z);
                a[14] += c * bflo(u1.w); a[15] += c * bfhi(u1.w);
            }
        }
    }

    // merge the 8 row-subgroups
#pragma unroll
    for (int k = 0; k < 16; k++) {
        a[k] += __shfl_xor(a[k], 4, 32);
        a[k] += __shfl_xor(a[k], 8, 32);
        a[k] += __shfl_xor(a[k], 16, 32);
    }

    float di = rsqrtf(1.0f + (float)deg);
    float dd = di * di;
    uint4 s0 = X0q[n * 4 + f], s1 = X1q[n * 4 + f];
    float4 bA0 = ((const float4*)bias)[2 * f];
    float4 bA1 = ((const float4*)bias)[2 * f + 1];
    float4 bB0 = ((const float4*)(bias + 32))[2 * f];
    float4 bB1 = ((const float4*)(bias + 32))[2 * f + 1];
    float v[16];
    v[0]  = di * a[0]  + dd * bflo(s0.x) + bA0.x;
    v[1]  = di * a[1]  + dd * bfhi(s0.x) + bA0.y;
    v[2]  = di * a[2]  + dd * bflo(s0.y) + bA0.z;
    v[3]  = di * a[3]  + dd * bfhi(s0.y) + bA0.w;
    v[4]  = di * a[4]  + dd * bflo(s0.z) + bA1.x;
    v[5]  = di * a[5]  + dd * bfhi(s0.z) + bA1.y;
    v[6]  = di * a[6]  + dd * bflo(s0.w) + bA1.z;
    v[7]  = di * a[7]  + dd * bfhi(s0.w) + bA1.w;
    v[8]  = di * a[8]  + dd * bflo(s1.x) + bB0.x;
    v[9]  = di * a[9]  + dd * bfhi(s1.x) + bB0.y;
    v[10] = di * a[10] + dd * bflo(s1.y) + bB0.z;
    v[11] = di * a[11] + dd * bfhi(s1.y) + bB0.w;
    v[12] = di * a[12] + dd * bflo(s1.z) + bB1.x;
    v[13] = di * a[13] + dd * bfhi(s1.z) + bB1.y;
    v[14] = di * a[14] + dd * bflo(s1.w) + bB1.z;
    v[15] = di * a[15] + dd * bfhi(s1.w) + bB1.w;
    if (RELU) {
#pragma unroll
        for (int k = 0; k < 16; k++) v[k] = fmaxf(v[k], 0.f);
    }
    if (NORM) {
        float s = 0.f;
#pragma unroll
        for (int k = 0; k < 16; k++) s += v[k] * v[k];
        s += __shfl_xor(s, 1, 32);
        s += __shfl_xor(s, 2, 32);
        float inv = 1.0f / fmaxf(sqrtf(s), 1e-12f);
#pragma unroll
        for (int k = 0; k < 16; k++) v[k] *= inv;
        if (g == 0) {
            O0q[n * 4 + f] = make_uint4(pack2(v[0], v[1]),  pack2(v[2], v[3]),
                                        pack2(v[4], v[5]),  pack2(v[6], v[7]));
            O1q[n * 4 + f] = make_uint4(pack2(v[8], v[9]),  pack2(v[10], v[11]),
                                        pack2(v[12], v[13]), pack2(v[14], v[15]));
        }
    } else {
        if (g == 0) {
            outFq[n * 8 + f]     = make_uint4(pack2(v[0], v[1]),  pack2(v[2], v[3]),
                                              pack2(v[4], v[5]),  pack2(v[6], v[7]));
            outFq[n * 8 + 4 + f] = make_uint4(pack2(v[8], v[9]),  pack2(v[10], v[11]),
                                              pack2(v[12], v[13]), pack2(v[14], v[15]));
        }
    }
}

// ---- fused edge dot (both halves) + finalize + symmetrize (NO atomics) ---
__global__ void k_dotsym(const uint4* __restrict__ H0q, const uint4* __restrict__ H1q,
                         const float* __restrict__ s_d, const int* __restrict__ j_idx,
                         const unsigned char* __restrict__ revb,
                         float* __restrict__ outS) {   // d_out + 2E, holds vals_s [2E]
    int t = blockIdx.x * 256 + threadIdx.x;   // NE*8 threads
    int e = t >> 3;
    int q = t & 7;
    int g = q >> 2, f = q & 3;
    int i = e / KNN;
    int j = j_idx[e];
    int node = g ? j : i;
    uint4 u0 = H0q[node * 4 + f];
    uint4 u1 = H1q[node * 4 + f];
    uint4 p0, p1;
    p0.x = __shfl_xor(u0.x, 4); p0.y = __shfl_xor(u0.y, 4);
    p0.z = __shfl_xor(u0.z, 4); p0.w = __shfl_xor(u0.w, 4);
    p1.x = __shfl_xor(u1.x, 4); p1.y = __shfl_xor(u1.y, 4);
    p1.z = __shfl_xor(u1.z, 4); p1.w = __shfl_xor(u1.w, 4);
    float s = bflo(u0.x) * bflo(p0.x) + bfhi(u0.x) * bfhi(p0.x)
            + bflo(u0.y) * bflo(p0.y) + bfhi(u0.y) * bfhi(p0.y)
            + bflo(u0.z) * bflo(p0.z) + bfhi(u0.z) * bfhi(p0.z)
            + bflo(u0.w) * bflo(p0.w) + bfhi(u0.w) * bfhi(p0.w)
            + bflo(u1.x) * bflo(p1.x) + bfhi(u1.x) * bfhi(p1.x)
            + bflo(u1.y) * bflo(p1.y) + bfhi(u1.y) * bfhi(p1.y)
            + bflo(u1.z) * bflo(p1.z) + bfhi(u1.z) * bfhi(p1.z)
            + bflo(u1.w) * bflo(p1.w) + bfhi(u1.w) * bfhi(p1.w);
    s += __shfl_xor(s, 1);
    s += __shfl_xor(s, 2);
    if (q == 0) {
        float base = OMEGA * fmaxf(s, 0.0f);
        int rt = revb[e];
        float vv, v2;
        if (rt != 255) {                     // reverse edge exists (rare)
            int rev = j * KNN + rt;
            vv = base + 0.5f * (1.0f - OMEGA) * (s_d[e] + s_d[rev]);
            v2 = 0.0f;
        } else {
            vv = base + (1.0f - OMEGA) * s_d[e];
            v2 = vv;
        }
        outS[e] = vv;
        outS[NE + e] = v2;
    }
}

// ---- binned in-edge accumulation + fused dinv2 ---------------------------
__global__ void k_jagg(const unsigned* __restrict__ jbbuf, const int* __restrict__ jbcnt,
                       const float* __restrict__ outS, float* __restrict__ dinv2,
                       const unsigned* __restrict__ jovf, const int* __restrict__ jovf_cnt,
                       const int* __restrict__ j_idx) {
    __shared__ float ld[512];
    int b = blockIdx.x;
    int tid = threadIdx.x;                   // 1024 threads
    if (tid < 512) ld[tid] = 0.0f;
    __syncthreads();
    const float* outSv2 = outS + NE;
    int n = min(jbcnt[b], JBCAP);
    for (int idx = tid; idx < n; idx += 1024) {
        unsigned p = jbbuf[b * JBCAP + idx];
        atomicAdd(&ld[p >> 20], outSv2[p & 0xFFFFFu]);
    }
    int m = jovf_cnt[0];                     // learner bin overflow (normally 0)
    for (int t2 = tid; t2 < m; t2 += 1024) {
        int e = (int)(jovf[t2] & 0xFFFFFu);
        int j = j_idx[e];
        if ((j >> 9) == b) atomicAdd(&ld[j & 511], outSv2[e]);
    }
    __syncthreads();
    if (tid < 512) {
        int node = b * 512 + tid;
        if (node < N_NODES) {
            float d = ld[tid];
            const float* pp = outS + node * KNN;
#pragma unroll
            for (int qq = 0; qq < KNN; qq++) d += pp[qq];
            dinv2[node] = (d > 0.0f) ? rsqrtf(fmaxf(d, 1e-12f)) : 0.0f;
        }
    }
}

// ---- final normalization: vals_norm = dinv2[r] * vals_s * dinv2[c] -------
__global__ void k_norm(const float* __restrict__ outS, const float* __restrict__ dinv2,
                       const int* __restrict__ j_idx, float* __restrict__ out) {
    int t = blockIdx.x * 256 + threadIdx.x;   // 2*NE threads
    int r, c;
    if (t < NE) { r = t / KNN; c = j_idx[t]; }
    else        { int e = t - NE; r = j_idx[e]; c = e / KNN; }
    out[t] = dinv2[r] * outS[t] * dinv2[c];
}

extern "C" void kernel_launch(void* const* d_in, const int* in_sizes, int n_in,
                              void* d_out, int out_size, void* d_ws, size_t ws_size,
                              hipStream_t stream) {
    const float* features = (const float*)d_in[0];
    const float* W1       = (const float*)d_in[1];
    const float* b1       = (const float*)d_in[2];
    const float* W2       = (const float*)d_in[3];
    const float* b2       = (const float*)d_in[4];
    const float* s_d      = (const float*)d_in[5];
    const int*   adj_row  = (const int*)d_in[6];
    const int*   adj_col  = (const int*)d_in[7];
    const int*   j_idx    = (const int*)d_in[9];
    float* out = (float*)d_out;

    const int N64 = N_NODES * 64;
    const int N32 = N_NODES * 32;
    // Workspace layout (zero region first, all offsets 16B-aligned):
    // [cnt N][ovfcnts 16][bcnt 80][jbcnt 80]  <- memset 0
    // [dinv2 N][A0 N32 us][A1 N32 us][B16 N64 us][H0 N32 us][H1 N32 us]
    // [ebuf N*CAP us][ovf NE u][revb NE uc][bbuf][jbbuf][ovf2 NE u][jovf NE u]
    int*   cnt     = (int*)d_ws;
    int*   ovfcnts = cnt + N_NODES;          // [0]=CAP ovf, [4]=adj bin ovf, [8]=learner bin ovf
    int*   bcnt    = ovfcnts + 16;
    int*   jbcnt   = bcnt + NBUCK;
    float* dinv2   = (float*)(jbcnt + NBUCK);
    unsigned short* A0  = (unsigned short*)(dinv2 + N_NODES);
    unsigned short* A1  = A0 + N32;
    unsigned short* B16 = A1 + N32;
    unsigned short* H0  = B16 + N64;
    unsigned short* H1  = H0 + N32;
    unsigned short* ebuf = H1 + N32;             // N*CAP ushorts
    unsigned* ovf    = (unsigned*)(ebuf + N_NODES * CAP);
    unsigned char* revb = (unsigned char*)(ovf + NE);
    unsigned* bbuf   = (unsigned*)(revb + NE);   // NBUCK*BCAP
    unsigned* jbbuf  = bbuf + NBUCK * BCAP;      // NBUCK*JBCAP
    unsigned* ovf2   = jbbuf + NBUCK * JBCAP;    // NE
    unsigned* jovf   = ovf2 + NE;                // NE

    // Re-init (ws is poisoned 0xAA before every call)
    size_t zero_bytes = (size_t)(N_NODES + 16 + 2 * NBUCK) * 4;
    hipMemsetAsync(cnt, 0, zero_bytes, stream);

    // Mega front end: gemm1 + bin(both sets) + reverse-edge scan (1 thr/edge)
    const int GB = N_NODES / 32;                          // 1250
    const int NBA = (NE + 256 * EPT - 1) / (256 * EPT);   // 469
    const int RB = NE / 256;                              // 3750
    k_mega1<<<GB + 2 * NBA + RB, 256, 0, stream>>>(
        features, W1, A0, A1, adj_row, adj_col, j_idx,
        bcnt, bbuf, ovf2, ovfcnts + 4, jbcnt, jbbuf, jovf, ovfcnts + 8, revb);

    // Per-bucket scatter (LDS slots, no global atomics) -> ebuf + cnt
    k_scatter3<<<NBUCK, 1024, 0, stream>>>(bbuf, bcnt, cnt, ebuf,
                                           ovf, ovfcnts, ovf2, ovfcnts + 4);

    // Layer 1 aggregate (dinv inline from cnt; overflow inline)
    k_aggf4<true, false><<<(N_NODES / 2 * 64 + 255) / 256, 256, 0, stream>>>(
        (const uint4*)A0, (const uint4*)A1, (uint4*)B16, nullptr, nullptr,
        cnt, ebuf, b1, ovf, ovfcnts);

    // Layer 2
    k_gemm2<<<N_NODES / 32, 256, 0, stream>>>(B16, W2, A0, A1);
    k_aggf4<false, true><<<(N_NODES / 2 * 64 + 255) / 256, 256, 0, stream>>>(
        (const uint4*)A0, (const uint4*)A1, nullptr, (uint4*)H0, (uint4*)H1,
        cnt, ebuf, b2, ovf, ovfcnts);

    // Fused edge scores + symmetrize (atomic-free, dual-half MLP)
    float* outS = out + 2 * NE;
    k_dotsym<<<NE * 8 / 256, 256, 0, stream>>>(
        (const uint4*)H0, (const uint4*)H1, s_d, j_idx, revb, outS);

    // Binned in-edge accumulation + dinv2, then final normalize
    k_jagg<<<NBUCK, 1024, 0, stream>>>(jbbuf, jbcnt, outS, dinv2, jovf, ovfcnts + 8, j_idx);
    k_norm<<<2 * NE / 256, 256, 0, stream>>>(outS, dinv2, j_idx, out);
}

// Round 13
// 236.439 us; speedup vs baseline: 1.3938x; 1.0660x over previous
//
#include <hip/hip_runtime.h>

// Problem constants (match reference)
#define N_NODES 40000
#define ISIZE   64
#define KNN     24
#define NE      (N_NODES * KNN)      // 960000 edges (= E_ADJ as well)
#define OMEGA   0.9f
#define CAP     64                   // per-node bucket capacity (max deg ~46)
#define NBUCK   80                   // buckets of 512 nodes (idx>>9)
#define BCAP    16384                // adj edges per bucket capacity (mean 12288)
#define JBCAP   16384                // learner edges per bucket capacity
#define EPT     8                    // edges per thread in bin pass

// ---- bf16 helpers (storage-only precision; all math in fp32) -------------
__device__ __forceinline__ float bf2f(unsigned short s) {
    return __uint_as_float(((unsigned)s) << 16);
}
__device__ __forceinline__ unsigned short f2bf(float f) {  // round-nearest-even
    unsigned u = __float_as_uint(f);
    u += 0x7fffu + ((u >> 16) & 1u);
    return (unsigned short)(u >> 16);
}
__device__ __forceinline__ float bflo(unsigned u) { return __uint_as_float(u << 16); }
__device__ __forceinline__ float bfhi(unsigned u) { return __uint_as_float(u & 0xffff0000u); }
__device__ __forceinline__ unsigned pack2(float lo, float hi) {
    return (unsigned)f2bf(lo) | ((unsigned)f2bf(hi) << 16);
}

// ---- mega front end: gemm layer1 | bin both edge sets | reverse scan -----
__global__ void k_mega1(const float* __restrict__ X, const float* __restrict__ W,
                        unsigned short* __restrict__ Y0, unsigned short* __restrict__ Y1,
                        const int* __restrict__ row, const int* __restrict__ col,
                        const int* __restrict__ j_idx,
                        int* __restrict__ bcnt, unsigned* __restrict__ bbuf,
                        unsigned* __restrict__ ovf2, int* __restrict__ ovf2_cnt,
                        int* __restrict__ jbcnt, unsigned* __restrict__ jbbuf,
                        unsigned* __restrict__ jovf, int* __restrict__ jovf_cnt,
                        unsigned char* __restrict__ revb) {
    __shared__ float sW[64 * 64];    // gemm: W tile | bin: lcnt/lbase overlay
    __shared__ float sX[32 * 64];
    const int GB  = N_NODES / 32;                          // 1250 gemm blocks
    const int NBA = (NE + 256 * EPT - 1) / (256 * EPT);    // 469 bin blocks per set
    int bx = blockIdx.x;
    int tid = threadIdx.x;
    if (bx < GB) {
        // ---- GEMM layer 1: rows bx*32.., split-half bf16 output ----
        int row0 = bx * 32;
        for (int t = tid; t < 1024; t += 256)
            ((float4*)sW)[t] = ((const float4*)W)[t];
        for (int t = tid; t < 512; t += 256)
            ((float4*)sX)[t] = ((const float4*)(X + row0 * 64))[t];
        __syncthreads();
        int cc = tid & 63;
        int rl = tid >> 6;
        for (int r = rl; r < 32; r += 4) {
            float acc = 0.0f;
#pragma unroll
            for (int kk = 0; kk < 64; kk++) acc += sX[r * 64 + kk] * sW[kk * 64 + cc];
            if (cc < 32) Y0[(row0 + r) * 32 + cc]      = f2bf(acc);
            else         Y1[(row0 + r) * 32 + cc - 32] = f2bf(acc);
        }
    } else if (bx < GB + 2 * NBA) {
        // ---- bin edges: adj by col (r<<16|c), learner by j ((j&511)<<20|e)
        int* lcnt  = (int*)sW;
        int* lbase = lcnt + NBUCK;
        int blk = bx - GB;
        bool adj = blk < NBA;
        if (!adj) blk -= NBA;
        for (int b = tid; b < NBUCK; b += 256) lcnt[b] = 0;
        __syncthreads();
        int e0 = blk * (256 * EPT);
        int myslot[EPT]; int myb[EPT]; unsigned myp[EPT];
        for (int k = 0; k < EPT; k++) {
            int e = e0 + k * 256 + tid;
            if (e < NE) {
                int b; unsigned p;
                if (adj) { int r = row[e], c = col[e]; b = c >> 9; p = ((unsigned)r << 16) | (unsigned)c; }
                else     { int j = j_idx[e];           b = j >> 9; p = ((unsigned)(j & 511) << 20) | (unsigned)e; }
                myb[k] = b; myp[k] = p;
                myslot[k] = atomicAdd(&lcnt[b], 1);
            } else myb[k] = -1;
        }
        __syncthreads();
        int* gcnt = adj ? bcnt : jbcnt;
        for (int b = tid; b < NBUCK; b += 256)
            lbase[b] = (lcnt[b] > 0) ? atomicAdd(&gcnt[b], lcnt[b]) : 0;
        __syncthreads();
        unsigned* gbuf = adj ? bbuf : jbbuf;
        unsigned* govf = adj ? ovf2 : jovf;
        int* gocnt = adj ? ovf2_cnt : jovf_cnt;
        for (int k = 0; k < EPT; k++) {
            if (myb[k] < 0) continue;
            int pos = lbase[myb[k]] + myslot[k];
            if (pos < BCAP) gbuf[myb[k] * BCAP + pos] = myp[k];
            else { int p = atomicAdd(gocnt, 1); govf[p] = myp[k]; }
        }
    } else {
        // ---- reverse-edge match: 1 thread/edge, 6 x uint4 over j's slice -
        int e = (bx - GB - 2 * NBA) * 256 + tid;   // NE threads
        int i = e / KNN;
        int j = j_idx[e];
        const uint4* jj4 = (const uint4*)(j_idx + j * KNN);  // 96B rows: 16B-aligned
        int rt = 255;
#pragma unroll
        for (int k = 5; k >= 0; k--) {             // descending so min index wins
            uint4 u = jj4[k];
            if ((int)u.w == i) rt = 4 * k + 3;
            if ((int)u.z == i) rt = 4 * k + 2;
            if ((int)u.y == i) rt = 4 * k + 1;
            if ((int)u.x == i) rt = 4 * k + 0;
        }
        revb[e] = (unsigned char)rt;
    }
}

// ---- per-bucket scatter: LDS slot assignment, NO global atomics ----------
__global__ void k_scatter3(const unsigned* __restrict__ bbuf, const int* __restrict__ bcnt,
                           int* __restrict__ cnt, unsigned short* __restrict__ ebuf,
                           unsigned* __restrict__ ovf, int* __restrict__ ovf_cnt,
                           const unsigned* __restrict__ ovf2, const int* __restrict__ ovf2_cnt) {
    __shared__ int lcnt2[512];
    int b = blockIdx.x;
    int tid = threadIdx.x;                   // 1024 threads
    if (tid < 512) lcnt2[tid] = 0;
    __syncthreads();
    int n = min(bcnt[b], BCAP);
    for (int idx = tid; idx < n; idx += 1024) {
        unsigned p = bbuf[b * BCAP + idx];
        int c = (int)(p & 0xffffu), r = (int)(p >> 16);
        int slot = atomicAdd(&lcnt2[c & 511], 1);
        if (slot < CAP) ebuf[c * CAP + slot] = (unsigned short)r;
        else { int q = atomicAdd(ovf_cnt, 1); ovf[q] = p; }
    }
    int m = ovf2_cnt[0];                     // adj bin overflow (normally 0)
    for (int idx = tid; idx < m; idx += 1024) {
        unsigned p = ovf2[idx];
        int c = (int)(p & 0xffffu), r = (int)(p >> 16);
        if ((c >> 9) != b) continue;
        int slot = atomicAdd(&lcnt2[c & 511], 1);
        if (slot < CAP) ebuf[c * CAP + slot] = (unsigned short)r;
        else { int q = atomicAdd(ovf_cnt, 1); ovf[q] = p; }
    }
    __syncthreads();
    if (tid < 512) {
        int node = b * 512 + tid;
        if (node < N_NODES) cnt[node] = lcnt2[tid];   // full degree (incl. >CAP)
    }
}

// ---- fused layer-1: pull-agg + self + bias + ReLU, then xW2 GEMM ---------
// 1024 threads = 16 waves = 32 nodes per block (2 nodes/wave, aggf4 scheme).
// B rows parked in LDS (fp32 - no intermediate rounding), W2 staged in LDS,
// then a 32x64x64 GEMM writes C halves (bf16). Deletes k_gemm2 + B16 array.
__global__ void __launch_bounds__(1024, 1)
k_aggemm1(const uint4* __restrict__ X0q, const uint4* __restrict__ X1q,
          const float* __restrict__ W2,
          unsigned short* __restrict__ C0, unsigned short* __restrict__ C1,
          const int* __restrict__ cnt,
          const unsigned short* __restrict__ ebuf, const float* __restrict__ bias,
          const unsigned* __restrict__ ovf, const int* __restrict__ ovf_cnt) {
    __shared__ float sW[64 * 64];     // 16 KB
    __shared__ float sB[32 * 64];     // 8 KB
    int tid  = threadIdx.x;
    int lane = tid & 63;
    int half = lane >> 5, sl = lane & 31;
    int nl = (tid >> 6) * 2 + half;   // local node 0..31
    int n  = blockIdx.x * 32 + nl;    // exact fit: 1250*32 == N_NODES

    // stage W2 (coalesced; no dependency until gemm phase)
    ((float4*)sW)[tid] = ((const float4*)W2)[tid];

    int deg = cnt[n];
    int bucketed = min(deg, CAP);
    int nb0 = min(bucketed, 32);
    int nb1 = bucketed - nb0;

    int   r0v = 0, r1v = 0;
    float d0v = 0.0f, d1v = 0.0f;
    if (sl < nb0) { r0v = (int)ebuf[n * CAP + sl];      d0v = rsqrtf(1.0f + (float)cnt[r0v]); }
    if (sl < nb1) { r1v = (int)ebuf[n * CAP + 32 + sl]; d1v = rsqrtf(1.0f + (float)cnt[r1v]); }

    int g = sl >> 2;          // row subgroup 0..7
    int f = sl & 3;           // uint4 quarter

    float a[16];
#pragma unroll
    for (int k = 0; k < 16; k++) a[k] = 0.f;
    int np0 = (nb0 + 7) >> 3;
    int np1 = (nb1 + 7) >> 3;

#pragma unroll 4
    for (int d = 0; d < np0; d++) {
        int   q = 8 * d + g;
        int   r = __shfl(r0v, q, 32);
        float c = __shfl(d0v, q, 32);
        uint4 u0 = X0q[r * 4 + f];
        uint4 u1 = X1q[r * 4 + f];
        a[0]  += c * bflo(u0.x); a[1]  += c * bfhi(u0.x);
        a[2]  += c * bflo(u0.y); a[3]  += c * bfhi(u0.y);
        a[4]  += c * bflo(u0.z); a[5]  += c * bfhi(u0.z);
        a[6]  += c * bflo(u0.w); a[7]  += c * bfhi(u0.w);
        a[8]  += c * bflo(u1.x); a[9]  += c * bfhi(u1.x);
        a[10] += c * bflo(u1.y); a[11] += c * bfhi(u1.y);
        a[12] += c * bflo(u1.z); a[13] += c * bfhi(u1.z);
        a[14] += c * bflo(u1.w); a[15] += c * bfhi(u1.w);
    }
#pragma unroll 4
    for (int d = 0; d < np1; d++) {
        int   q = 8 * d + g;
        int   r = __shfl(r1v, q, 32);
        float c = __shfl(d1v, q, 32);
        uint4 u0 = X0q[r * 4 + f];
        uint4 u1 = X1q[r * 4 + f];
        a[0]  += c * bflo(u0.x); a[1]  += c * bfhi(u0.x);
        a[2]  += c * bflo(u0.y); a[3]  += c * bfhi(u0.y);
        a[4]  += c * bflo(u0.z); a[5]  += c * bfhi(u0.z);
        a[6]  += c * bflo(u0.w); a[7]  += c * bfhi(u0.w);
        a[8]  += c * bflo(u1.x); a[9]  += c * bfhi(u1.x);
        a[10] += c * bflo(u1.y); a[11] += c * bfhi(u1.y);
        a[12] += c * bflo(u1.z); a[13] += c * bfhi(u1.z);
        a[14] += c * bflo(u1.w); a[15] += c * bfhi(u1.w);
    }
    if (deg > CAP) {                         // CAP overflow (normally none)
        int m = ovf_cnt[0];
        for (int k2 = 0; k2 < m; k2++) {
            unsigned p = ovf[k2];
            if ((int)(p & 0xffffu) == n && g == 0) {
                int r = (int)(p >> 16);
                float c = rsqrtf(1.0f + (float)cnt[r]);
                uint4 u0 = X0q[r * 4 + f], u1 = X1q[r * 4 + f];
                a[0]  += c * bflo(u0.x); a[1]  += c * bfhi(u0.x);
                a[2]  += c * bflo(u0.y); a[3]  += c * bfhi(u0.y);
                a[4]  += c * bflo(u0.z); a[5]  += c * bfhi(u0.z);
                a[6]  += c * bflo(u0.w); a[7]  += c * bfhi(u0.w);
                a[8]  += c * bflo(u1.x); a[9]  += c * bfhi(u1.x);
                a[10] += c * bflo(u1.y); a[11] += c * bfhi(u1.y);
                a[12] += c * bflo(u1.z); a[13] += c * bfhi(u1.z);
                a[14] += c * bflo(u1.w); a[15] += c * bfhi(u1.w);
            }
        }
    }
#pragma unroll
    for (int k = 0; k < 16; k++) {
        a[k] += __shfl_xor(a[k], 4, 32);
        a[k] += __shfl_xor(a[k], 8, 32);
        a[k] += __shfl_xor(a[k], 16, 32);
    }

    float di = rsqrtf(1.0f + (float)deg);
    float dd = di * di;
    uint4 s0 = X0q[n * 4 + f], s1 = X1q[n * 4 + f];
    float4 bA0 = ((const float4*)bias)[2 * f];
    float4 bA1 = ((const float4*)bias)[2 * f + 1];
    float4 bB0 = ((const float4*)(bias + 32))[2 * f];
    float4 bB1 = ((const float4*)(bias + 32))[2 * f + 1];
    if (g == 0) {
        float* dst = sB + nl * 64 + 8 * f;
        dst[0] = fmaxf(di * a[0]  + dd * bflo(s0.x) + bA0.x, 0.f);
        dst[1] = fmaxf(di * a[1]  + dd * bfhi(s0.x) + bA0.y, 0.f);
        dst[2] = fmaxf(di * a[2]  + dd * bflo(s0.y) + bA0.z, 0.f);
        dst[3] = fmaxf(di * a[3]  + dd * bfhi(s0.y) + bA0.w, 0.f);
        dst[4] = fmaxf(di * a[4]  + dd * bflo(s0.z) + bA1.x, 0.f);
        dst[5] = fmaxf(di * a[5]  + dd * bfhi(s0.z) + bA1.y, 0.f);
        dst[6] = fmaxf(di * a[6]  + dd * bflo(s0.w) + bA1.z, 0.f);
        dst[7] = fmaxf(di * a[7]  + dd * bfhi(s0.w) + bA1.w, 0.f);
        float* dst2 = dst + 32;
        dst2[0] = fmaxf(di * a[8]  + dd * bflo(s1.x) + bB0.x, 0.f);
        dst2[1] = fmaxf(di * a[9]  + dd * bfhi(s1.x) + bB0.y, 0.f);
        dst2[2] = fmaxf(di * a[10] + dd * bflo(s1.y) + bB0.z, 0.f);
        dst2[3] = fmaxf(di * a[11] + dd * bfhi(s1.y) + bB0.w, 0.f);
        dst2[4] = fmaxf(di * a[12] + dd * bflo(s1.z) + bB1.x, 0.f);
        dst2[5] = fmaxf(di * a[13] + dd * bfhi(s1.z) + bB1.y, 0.f);
        dst2[6] = fmaxf(di * a[14] + dd * bflo(s1.w) + bB1.z, 0.f);
        dst2[7] = fmaxf(di * a[15] + dd * bfhi(s1.w) + bB1.w, 0.f);
    }
    __syncthreads();

    // ---- GEMM: C[32x64] = sB[32x64] @ sW[64x64], 2 rows/thread ----------
    int col = tid & 63;
    int r0  = tid >> 6;           // 0..15; rows r0 and r0+16
    float acc0 = 0.f, acc1 = 0.f;
#pragma unroll
    for (int kk = 0; kk < 64; kk++) {
        float wv = sW[kk * 64 + col];
        acc0 += sB[r0 * 64 + kk] * wv;
        acc1 += sB[(r0 + 16) * 64 + kk] * wv;
    }
    int na = blockIdx.x * 32 + r0;
    int nb = na + 16;
    if (col < 32) {
        C0[na * 32 + col] = f2bf(acc0);
        C0[nb * 32 + col] = f2bf(acc1);
    } else {
        C1[na * 32 + col - 32] = f2bf(acc0);
        C1[nb * 32 + col - 32] = f2bf(acc1);
    }
}

// ---- layer-2 pull aggregation (normalize epilogue), aggf4 scheme ---------
__global__ void k_aggf4(const uint4* __restrict__ X0q, const uint4* __restrict__ X1q,
                        uint4* __restrict__ O0q, uint4* __restrict__ O1q,
                        const int* __restrict__ cnt,
                        const unsigned short* __restrict__ ebuf, const float* __restrict__ bias,
                        const unsigned* __restrict__ ovf, const int* __restrict__ ovf_cnt) {
    int w = (blockIdx.x * 256 + threadIdx.x) >> 6;   // wave id, 2 nodes/wave
    int lane = threadIdx.x & 63;
    int half = lane >> 5, sl = lane & 31;
    int n = w * 2 + half;
    if (n >= N_NODES) return;
    int deg = cnt[n];
    int bucketed = min(deg, CAP);
    int nb0 = min(bucketed, 32);
    int nb1 = bucketed - nb0;

    int   r0v = 0, r1v = 0;
    float d0v = 0.0f, d1v = 0.0f;
    if (sl < nb0) { r0v = (int)ebuf[n * CAP + sl];      d0v = rsqrtf(1.0f + (float)cnt[r0v]); }
    if (sl < nb1) { r1v = (int)ebuf[n * CAP + 32 + sl]; d1v = rsqrtf(1.0f + (float)cnt[r1v]); }

    int g = sl >> 2;
    int f = sl & 3;

    float a[16];
#pragma unroll
    for (int k = 0; k < 16; k++) a[k] = 0.f;
    int np0 = (nb0 + 7) >> 3;
    int np1 = (nb1 + 7) >> 3;

#pragma unroll 4
    for (int d = 0; d < np0; d++) {
        int   q = 8 * d + g;
        int   r = __shfl(r0v, q, 32);
        float c = __shfl(d0v, q, 32);
        uint4 u0 = X0q[r * 4 + f];
        uint4 u1 = X1q[r * 4 + f];
        a[0]  += c * bflo(u0.x); a[1]  += c * bfhi(u0.x);
        a[2]  += c * bflo(u0.y); a[3]  += c * bfhi(u0.y);
        a[4]  += c * bflo(u0.z); a[5]  += c * bfhi(u0.z);
        a[6]  += c * bflo(u0.w); a[7]  += c * bfhi(u0.w);
        a[8]  += c * bflo(u1.x); a[9]  += c * bfhi(u1.x);
        a[10] += c * bflo(u1.y); a[11] += c * bfhi(u1.y);
        a[12] += c * bflo(u1.z); a[13] += c * bfhi(u1.z);
        a[14] += c * bflo(u1.w); a[15] += c * bfhi(u1.w);
    }
#pragma unroll 4
    for (int d = 0; d < np1; d++) {
        int   q = 8 * d + g;
        int   r = __shfl(r1v, q, 32);
        float c = __shfl(d1v, q, 32);
        uint4 u0 = X0q[r * 4 + f];
        uint4 u1 = X1q[r * 4 + f];
        a[0]  += c * bflo(u0.x); a[1]  += c * bfhi(u0.x);
        a[2]  += c * bflo(u0.y); a[3]  += c * bfhi(u0.y);
        a[4]  += c * bflo(u0.z); a[5]  += c * bfhi(u0.z);
        a[6]  += c * bflo(u0.w); a[7]  += c * bfhi(u0.w);
        a[8]  += c * bflo(u1.x); a[9]  += c * bfhi(u1.x);
        a[10] += c * bflo(u1.y); a[11] += c * bfhi(u1.y);
        a[12] += c * bflo(u1.z); a[13] += c * bfhi(u1.z);
        a[14] += c * bflo(u1.w); a[15] += c * bfhi(u1.w);
    }
    if (deg > CAP) {
        int m = ovf_cnt[0];
        for (int k2 = 0; k2 < m; k2++) {
            unsigned p = ovf[k2];
            if ((int)(p & 0xffffu) == n && g == 0) {
                int r = (int)(p >> 16);
                float c = rsqrtf(1.0f + (float)cnt[r]);
                uint4 u0 = X0q[r * 4 + f], u1 = X1q[r * 4 + f];
                a[0]  += c * bflo(u0.x); a[1]  += c * bfhi(u0.x);
                a[2]  += c * bflo(u0.y); a[3]  += c * bfhi(u0.y);
                a[4]  += c * bflo(u0.z); a[5]  += c * bfhi(u0.z);
                a[6]  += c * bflo(u0.w); a[7]  += c * bfhi(u0.w);
                a[8]  += c * bflo(u1.x); a[9]  += c * bfhi(u1.x);
                a[10] += c * bflo(u1.y); a[11] += c * bfhi(u1.y);
                a[12] += c * bflo(u1.z); a[13] += c * bfhi(u1.z);
                a[14] += c * bflo(u1.w); a[15] += c * bfhi(u1.w);
            }
        }
    }
#pragma unroll
    for (int k = 0; k < 16; k++) {
        a[k] += __shfl_xor(a[k], 4, 32);
        a[k] += __shfl_xor(a[k], 8, 32);
        a[k] += __shfl_xor(a[k], 16, 32);
    }

    float di = rsqrtf(1.0f + (float)deg);
    float dd = di * di;
    uint4 s0 = X0q[n * 4 + f], s1 = X1q[n * 4 + f];
    float4 bA0 = ((const float4*)bias)[2 * f];
    float4 bA1 = ((const float4*)bias)[2 * f + 1];
    float4 bB0 = ((const float4*)(bias + 32))[2 * f];
    float4 bB1 = ((const float4*)(bias + 32))[2 * f + 1];
    float v[16];
    v[0]  = di * a[0]  + dd * bflo(s0.x) + bA0.x;
    v[1]  = di * a[1]  + dd * bfhi(s0.x) + bA0.y;
    v[2]  = di * a[2]  + dd * bflo(s0.y) + bA0.z;
    v[3]  = di * a[3]  + dd * bfhi(s0.y) + bA0.w;
    v[4]  = di * a[4]  + dd * bflo(s0.z) + bA1.x;
    v[5]  = di * a[5]  + dd * bfhi(s0.z) + bA1.y;
    v[6]  = di * a[6]  + dd * bflo(s0.w) + bA1.z;
    v[7]  = di * a[7]  + dd * bfhi(s0.w) + bA1.w;
    v[8]  = di * a[8]  + dd * bflo(s1.x) + bB0.x;
    v[9]  = di * a[9]  + dd * bfhi(s1.x) + bB0.y;
    v[10] = di * a[10] + dd * bflo(s1.y) + bB0.z;
    v[11] = di * a[11] + dd * bfhi(s1.y) + bB0.w;
    v[12] = di * a[12] + dd * bflo(s1.z) + bB1.x;
    v[13] = di * a[13] + dd * bfhi(s1.z) + bB1.y;
    v[14] = di * a[14] + dd * bflo(s1.w) + bB1.z;
    v[15] = di * a[15] + dd * bfhi(s1.w) + bB1.w;

    float s = 0.f;
#pragma unroll
    for (int k = 0; k < 16; k++) s += v[k] * v[k];
    s += __shfl_xor(s, 1, 32);
    s += __shfl_xor(s, 2, 32);
    float inv = 1.0f / fmaxf(sqrtf(s), 1e-12f);
#pragma unroll
    for (int k = 0; k < 16; k++) v[k] *= inv;
    if (g == 0) {
        O0q[n * 4 + f] = make_uint4(pack2(v[0], v[1]),  pack2(v[2], v[3]),
                                    pack2(v[4], v[5]),  pack2(v[6], v[7]));
        O1q[n * 4 + f] = make_uint4(pack2(v[8], v[9]),  pack2(v[10], v[11]),
                                    pack2(v[12], v[13]), pack2(v[14], v[15]));
    }
}

// ---- fused edge dot + finalize + symmetrize: 4 lanes/edge, in-lane dots --
// Each lane loads i AND j quarters of both halves (4 loads, 2 random) and
// computes the partial dot locally - no partner shuffles, 2x random MLP.
__global__ void k_dotsym(const uint4* __restrict__ H0q, const uint4* __restrict__ H1q,
                         const float* __restrict__ s_d, const int* __restrict__ j_idx,
                         const unsigned char* __restrict__ revb,
                         float* __restrict__ outS) {   // d_out + 2E, holds vals_s [2E]
    int t = blockIdx.x * 256 + threadIdx.x;   // NE*4 threads
    int e = t >> 2;
    int f = t & 3;
    int i = e / KNN;
    int j = j_idx[e];
    uint4 a0 = H0q[i * 4 + f];
    uint4 b0 = H0q[j * 4 + f];
    uint4 a1 = H1q[i * 4 + f];
    uint4 b1 = H1q[j * 4 + f];
    float s = bflo(a0.x) * bflo(b0.x) + bfhi(a0.x) * bfhi(b0.x)
            + bflo(a0.y) * bflo(b0.y) + bfhi(a0.y) * bfhi(b0.y)
            + bflo(a0.z) * bflo(b0.z) + bfhi(a0.z) * bfhi(b0.z)
            + bflo(a0.w) * bflo(b0.w) + bfhi(a0.w) * bfhi(b0.w)
            + bflo(a1.x) * bflo(b1.x) + bfhi(a1.x) * bfhi(b1.x)
            + bflo(a1.y) * bflo(b1.y) + bfhi(a1.y) * bfhi(b1.y)
            + bflo(a1.z) * bflo(b1.z) + bfhi(a1.z) * bfhi(b1.z)
            + bflo(a1.w) * bflo(b1.w) + bfhi(a1.w) * bfhi(b1.w);
    s += __shfl_xor(s, 1);
    s += __shfl_xor(s, 2);
    if (f == 0) {
        float base = OMEGA * fmaxf(s, 0.0f);
        int rt = revb[e];
        float vv, v2;
        if (rt != 255) {                     // reverse edge exists (rare)
            int rev = j * KNN + rt;
            vv = base + 0.5f * (1.0f - OMEGA) * (s_d[e] + s_d[rev]);
            v2 = 0.0f;
        } else {
            vv = base + (1.0f - OMEGA) * s_d[e];
            v2 = vv;
        }
        outS[e] = vv;
        outS[NE + e] = v2;
    }
}

// ---- binned in-edge accumulation + fused dinv2 ---------------------------
__global__ void k_jagg(const unsigned* __restrict__ jbbuf, const int* __restrict__ jbcnt,
                       const float* __restrict__ outS, float* __restrict__ dinv2,
                       const unsigned* __restrict__ jovf, const int* __restrict__ jovf_cnt,
                       const int* __restrict__ j_idx) {
    __shared__ float ld[512];
    int b = blockIdx.x;
    int tid = threadIdx.x;                   // 1024 threads
    if (tid < 512) ld[tid] = 0.0f;
    __syncthreads();
    const float* outSv2 = outS + NE;
    int n = min(jbcnt[b], JBCAP);
    for (int idx = tid; idx < n; idx += 1024) {
        unsigned p = jbbuf[b * JBCAP + idx];
        atomicAdd(&ld[p >> 20], outSv2[p & 0xFFFFFu]);
    }
    int m = jovf_cnt[0];                     // learner bin overflow (normally 0)
    for (int t2 = tid; t2 < m; t2 += 1024) {
        int e = (int)(jovf[t2] & 0xFFFFFu);
        int j = j_idx[e];
        if ((j >> 9) == b) atomicAdd(&ld[j & 511], outSv2[e]);
    }
    __syncthreads();
    if (tid < 512) {
        int node = b * 512 + tid;
        if (node < N_NODES) {
            float d = ld[tid];
            const float* pp = outS + node * KNN;
#pragma unroll
            for (int qq = 0; qq < KNN; qq++) d += pp[qq];
            dinv2[node] = (d > 0.0f) ? rsqrtf(fmaxf(d, 1e-12f)) : 0.0f;
        }
    }
}

// ---- final normalization: vals_norm = dinv2[r] * vals_s * dinv2[c] -------
__global__ void k_norm(const float* __restrict__ outS, const float* __restrict__ dinv2,
                       const int* __restrict__ j_idx, float* __restrict__ out) {
    int t = blockIdx.x * 256 + threadIdx.x;   // 2*NE threads
    int r, c;
    if (t < NE) { r = t / KNN; c = j_idx[t]; }
    else        { int e = t - NE; r = j_idx[e]; c = e / KNN; }
    out[t] = dinv2[r] * outS[t] * dinv2[c];
}

extern "C" void kernel_launch(void* const* d_in, const int* in_sizes, int n_in,
                              void* d_out, int out_size, void* d_ws, size_t ws_size,
                              hipStream_t stream) {
    const float* features = (const float*)d_in[0];
    const float* W1       = (const float*)d_in[1];
    const float* b1       = (const float*)d_in[2];
    const float* W2       = (const float*)d_in[3];
    const float* b2       = (const float*)d_in[4];
    const float* s_d      = (const float*)d_in[5];
    const int*   adj_row  = (const int*)d_in[6];
    const int*   adj_col  = (const int*)d_in[7];
    const int*   j_idx    = (const int*)d_in[9];
    float* out = (float*)d_out;

    const int N32 = N_NODES * 32;
    // Workspace layout (zero region first, all offsets 16B-aligned):
    // [cnt N][ovfcnts 16][bcnt 80][jbcnt 80]  <- memset 0
    // [dinv2 N][A0 N32 us][A1 N32 us][C0 N32 us][C1 N32 us][H0 N32 us][H1 N32 us]
    // [ebuf N*CAP us][ovf NE u][revb NE uc][bbuf][jbbuf][ovf2 NE u][jovf NE u]
    int*   cnt     = (int*)d_ws;
    int*   ovfcnts = cnt + N_NODES;          // [0]=CAP ovf, [4]=adj bin ovf, [8]=learner bin ovf
    int*   bcnt    = ovfcnts + 16;
    int*   jbcnt   = bcnt + NBUCK;
    float* dinv2   = (float*)(jbcnt + NBUCK);
    unsigned short* A0  = (unsigned short*)(dinv2 + N_NODES);
    unsigned short* A1  = A0 + N32;
    unsigned short* C0  = A1 + N32;
    unsigned short* C1  = C0 + N32;
    unsigned short* H0  = C1 + N32;
    unsigned short* H1  = H0 + N32;
    unsigned short* ebuf = H1 + N32;             // N*CAP ushorts
    unsigned* ovf    = (unsigned*)(ebuf + N_NODES * CAP);
    unsigned char* revb = (unsigned char*)(ovf + NE);
    unsigned* bbuf   = (unsigned*)(revb + NE);   // NBUCK*BCAP
    unsigned* jbbuf  = bbuf + NBUCK * BCAP;      // NBUCK*JBCAP
    unsigned* ovf2   = jbbuf + NBUCK * JBCAP;    // NE
    unsigned* jovf   = ovf2 + NE;                // NE

    // Re-init (ws is poisoned 0xAA before every call)
    size_t zero_bytes = (size_t)(N_NODES + 16 + 2 * NBUCK) * 4;
    hipMemsetAsync(cnt, 0, zero_bytes, stream);

    // Mega front end: gemm1 + bin(both sets) + reverse-edge scan (1 thr/edge)
    const int GB = N_NODES / 32;                          // 1250
    const int NBA = (NE + 256 * EPT - 1) / (256 * EPT);   // 469
    const int RB = NE / 256;                              // 3750
    k_mega1<<<GB + 2 * NBA + RB, 256, 0, stream>>>(
        features, W1, A0, A1, adj_row, adj_col, j_idx,
        bcnt, bbuf, ovf2, ovfcnts + 4, jbcnt, jbbuf, jovf, ovfcnts + 8, revb);

    // Per-bucket scatter (LDS slots, no global atomics) -> ebuf + cnt
    k_scatter3<<<NBUCK, 1024, 0, stream>>>(bbuf, bcnt, cnt, ebuf,
                                           ovf, ovfcnts, ovf2, ovfcnts + 4);

    // Fused layer-1: agg(A)+ReLU -> LDS -> xW2 -> C halves
    k_aggemm1<<<N_NODES / 32, 1024, 0, stream>>>(
        (const uint4*)A0, (const uint4*)A1, W2, C0, C1,
        cnt, ebuf, b1, ovf, ovfcnts);

    // Layer-2 aggregate + normalize -> H halves
    k_aggf4<<<(N_NODES / 2 * 64 + 255) / 256, 256, 0, stream>>>(
        (const uint4*)C0, (const uint4*)C1, (uint4*)H0, (uint4*)H1,
        cnt, ebuf, b2, ovf, ovfcnts);

    // Fused edge scores + symmetrize (atomic-free, 4 lanes/edge in-lane dots)
    float* outS = out + 2 * NE;
    k_dotsym<<<NE * 4 / 256, 256, 0, stream>>>(
        (const uint4*)H0, (const uint4*)H1, s_d, j_idx, revb, outS);

    // Binned in-edge accumulation + dinv2, then final normalize
    k_jagg<<<NBUCK, 1024, 0, stream>>>(jbbuf, jbcnt, outS, dinv2, jovf, ovfcnts + 8, j_idx);
    k_norm<<<2 * NE / 256, 256, 0, stream>>>(outS, dinv2, j_idx, out);
}

// Round 14
// 235.446 us; speedup vs baseline: 1.3997x; 1.0042x over previous
//
#include <hip/hip_runtime.h>

// Problem constants (match reference)
#define N_NODES 40000
#define ISIZE   64
#define KNN     24
#define NE      (N_NODES * KNN)      // 960000 edges (= E_ADJ as well)
#define OMEGA   0.9f
#define CAP     64                   // per-node bucket capacity (max deg ~46)
#define NBUCK   80                   // buckets of 512 nodes (idx>>9)
#define BCAP    16384                // adj edges per bucket capacity (mean 12288)
#define JBCAP   16384                // learner edges per bucket capacity
#define EPT     8                    // edges per thread in bin pass

// ---- bf16 helpers (storage-only precision; all math in fp32) -------------
__device__ __forceinline__ float bf2f(unsigned short s) {
    return __uint_as_float(((unsigned)s) << 16);
}
__device__ __forceinline__ unsigned short f2bf(float f) {  // round-nearest-even
    unsigned u = __float_as_uint(f);
    u += 0x7fffu + ((u >> 16) & 1u);
    return (unsigned short)(u >> 16);
}
__device__ __forceinline__ float bflo(unsigned u) { return __uint_as_float(u << 16); }
__device__ __forceinline__ float bfhi(unsigned u) { return __uint_as_float(u & 0xffff0000u); }
__device__ __forceinline__ unsigned pack2(float lo, float hi) {
    return (unsigned)f2bf(lo) | ((unsigned)f2bf(hi) << 16);
}
__device__ __forceinline__ float dot8(uint4 a, uint4 b) {
    return bflo(a.x) * bflo(b.x) + bfhi(a.x) * bfhi(b.x)
         + bflo(a.y) * bflo(b.y) + bfhi(a.y) * bfhi(b.y)
         + bflo(a.z) * bflo(b.z) + bfhi(a.z) * bfhi(b.z)
         + bflo(a.w) * bflo(b.w) + bfhi(a.w) * bfhi(b.w);
}

// ---- mega front end: gemm layer1 | bin both edge sets | reverse scan -----
// Node feature rows are stored MERGED: 64 bf16 = 128 B per row (uint4 x 8).
__global__ void k_mega1(const float* __restrict__ X, const float* __restrict__ W,
                        unsigned short* __restrict__ Y,
                        const int* __restrict__ row, const int* __restrict__ col,
                        const int* __restrict__ j_idx,
                        int* __restrict__ bcnt, unsigned* __restrict__ bbuf,
                        unsigned* __restrict__ ovf2, int* __restrict__ ovf2_cnt,
                        int* __restrict__ jbcnt, unsigned* __restrict__ jbbuf,
                        unsigned* __restrict__ jovf, int* __restrict__ jovf_cnt,
                        unsigned char* __restrict__ revb) {
    __shared__ float sW[64 * 64];    // gemm: W tile | bin: lcnt/lbase overlay
    __shared__ float sX[32 * 64];
    const int GB  = N_NODES / 32;                          // 1250 gemm blocks
    const int NBA = (NE + 256 * EPT - 1) / (256 * EPT);    // 469 bin blocks per set
    int bx = blockIdx.x;
    int tid = threadIdx.x;
    if (bx < GB) {
        // ---- GEMM layer 1: rows bx*32.., merged bf16 output ----
        int row0 = bx * 32;
        for (int t = tid; t < 1024; t += 256)
            ((float4*)sW)[t] = ((const float4*)W)[t];
        for (int t = tid; t < 512; t += 256)
            ((float4*)sX)[t] = ((const float4*)(X + row0 * 64))[t];
        __syncthreads();
        int cc = tid & 63;
        int rl = tid >> 6;
        for (int r = rl; r < 32; r += 4) {
            float acc = 0.0f;
#pragma unroll
            for (int kk = 0; kk < 64; kk++) acc += sX[r * 64 + kk] * sW[kk * 64 + cc];
            Y[(row0 + r) * 64 + cc] = f2bf(acc);
        }
    } else if (bx < GB + 2 * NBA) {
        // ---- bin edges: adj by col (r<<16|c), learner by j ((j&511)<<20|e)
        int* lcnt  = (int*)sW;
        int* lbase = lcnt + NBUCK;
        int blk = bx - GB;
        bool adj = blk < NBA;
        if (!adj) blk -= NBA;
        for (int b = tid; b < NBUCK; b += 256) lcnt[b] = 0;
        __syncthreads();
        int e0 = blk * (256 * EPT);
        int myslot[EPT]; int myb[EPT]; unsigned myp[EPT];
        for (int k = 0; k < EPT; k++) {
            int e = e0 + k * 256 + tid;
            if (e < NE) {
                int b; unsigned p;
                if (adj) { int r = row[e], c = col[e]; b = c >> 9; p = ((unsigned)r << 16) | (unsigned)c; }
                else     { int j = j_idx[e];           b = j >> 9; p = ((unsigned)(j & 511) << 20) | (unsigned)e; }
                myb[k] = b; myp[k] = p;
                myslot[k] = atomicAdd(&lcnt[b], 1);
            } else myb[k] = -1;
        }
        __syncthreads();
        int* gcnt = adj ? bcnt : jbcnt;
        for (int b = tid; b < NBUCK; b += 256)
            lbase[b] = (lcnt[b] > 0) ? atomicAdd(&gcnt[b], lcnt[b]) : 0;
        __syncthreads();
        unsigned* gbuf = adj ? bbuf : jbbuf;
        unsigned* govf = adj ? ovf2 : jovf;
        int* gocnt = adj ? ovf2_cnt : jovf_cnt;
        for (int k = 0; k < EPT; k++) {
            if (myb[k] < 0) continue;
            int pos = lbase[myb[k]] + myslot[k];
            if (pos < BCAP) gbuf[myb[k] * BCAP + pos] = myp[k];
            else { int p = atomicAdd(gocnt, 1); govf[p] = myp[k]; }
        }
    } else {
        // ---- reverse-edge match: 1 thread/edge, 6 x uint4 over j's slice -
        int e = (bx - GB - 2 * NBA) * 256 + tid;   // NE threads
        int i = e / KNN;
        int j = j_idx[e];
        const uint4* jj4 = (const uint4*)(j_idx + j * KNN);  // 96B rows: 16B-aligned
        int rt = 255;
#pragma unroll
        for (int k = 5; k >= 0; k--) {             // descending so min index wins
            uint4 u = jj4[k];
            if ((int)u.w == i) rt = 4 * k + 3;
            if ((int)u.z == i) rt = 4 * k + 2;
            if ((int)u.y == i) rt = 4 * k + 1;
            if ((int)u.x == i) rt = 4 * k + 0;
        }
        revb[e] = (unsigned char)rt;
    }
}

// ---- per-bucket scatter: LDS slot assignment, NO global atomics ----------
__global__ void k_scatter3(const unsigned* __restrict__ bbuf, const int* __restrict__ bcnt,
                           int* __restrict__ cnt, unsigned short* __restrict__ ebuf,
                           unsigned* __restrict__ ovf, int* __restrict__ ovf_cnt,
                           const unsigned* __restrict__ ovf2, const int* __restrict__ ovf2_cnt) {
    __shared__ int lcnt2[512];
    int b = blockIdx.x;
    int tid = threadIdx.x;                   // 1024 threads
    if (tid < 512) lcnt2[tid] = 0;
    __syncthreads();
    int n = min(bcnt[b], BCAP);
    for (int idx = tid; idx < n; idx += 1024) {
        unsigned p = bbuf[b * BCAP + idx];
        int c = (int)(p & 0xffffu), r = (int)(p >> 16);
        int slot = atomicAdd(&lcnt2[c & 511], 1);
        if (slot < CAP) ebuf[c * CAP + slot] = (unsigned short)r;
        else { int q = atomicAdd(ovf_cnt, 1); ovf[q] = p; }
    }
    int m = ovf2_cnt[0];                     // adj bin overflow (normally 0)
    for (int idx = tid; idx < m; idx += 1024) {
        unsigned p = ovf2[idx];
        int c = (int)(p & 0xffffu), r = (int)(p >> 16);
        if ((c >> 9) != b) continue;
        int slot = atomicAdd(&lcnt2[c & 511], 1);
        if (slot < CAP) ebuf[c * CAP + slot] = (unsigned short)r;
        else { int q = atomicAdd(ovf_cnt, 1); ovf[q] = p; }
    }
    __syncthreads();
    if (tid < 512) {
        int node = b * 512 + tid;
        if (node < N_NODES) cnt[node] = lcnt2[tid];   // full degree (incl. >CAP)
    }
}

// ---- fused layer-1: pull-agg + self + bias + ReLU, then xW2 GEMM ---------
// 1024 threads = 16 waves = 32 nodes per block (2 nodes/wave).
// Merged 128B rows: per gathered row, 2 ADJACENT uint4 loads (one L2 line).
__global__ void __launch_bounds__(1024, 1)
k_aggemm1(const uint4* __restrict__ Aq, const float* __restrict__ W2,
          unsigned short* __restrict__ C,
          const int* __restrict__ cnt,
          const unsigned short* __restrict__ ebuf, const float* __restrict__ bias,
          const unsigned* __restrict__ ovf, const int* __restrict__ ovf_cnt) {
    __shared__ float sW[64 * 64];     // 16 KB
    __shared__ float sB[32 * 64];     // 8 KB
    int tid  = threadIdx.x;
    int lane = tid & 63;
    int half = lane >> 5, sl = lane & 31;
    int nl = (tid >> 6) * 2 + half;   // local node 0..31
    int n  = blockIdx.x * 32 + nl;    // exact fit: 1250*32 == N_NODES

    // stage W2 (coalesced; no dependency until gemm phase)
    ((float4*)sW)[tid] = ((const float4*)W2)[tid];

    int deg = cnt[n];
    int bucketed = min(deg, CAP);
    int nb0 = min(bucketed, 32);
    int nb1 = bucketed - nb0;

    int   r0v = 0, r1v = 0;
    float d0v = 0.0f, d1v = 0.0f;
    if (sl < nb0) { r0v = (int)ebuf[n * CAP + sl];      d0v = rsqrtf(1.0f + (float)cnt[r0v]); }
    if (sl < nb1) { r1v = (int)ebuf[n * CAP + 32 + sl]; d1v = rsqrtf(1.0f + (float)cnt[r1v]); }

    int g = sl >> 2;          // row subgroup 0..7
    int f = sl & 3;           // uint4 quarter

    float a[16];
#pragma unroll
    for (int k = 0; k < 16; k++) a[k] = 0.f;
    int np0 = (nb0 + 7) >> 3;
    int np1 = (nb1 + 7) >> 3;

#pragma unroll 4
    for (int d = 0; d < np0; d++) {
        int   q = 8 * d + g;
        int   r = __shfl(r0v, q, 32);
        float c = __shfl(d0v, q, 32);
        uint4 u0 = Aq[r * 8 + f];
        uint4 u1 = Aq[r * 8 + 4 + f];
        a[0]  += c * bflo(u0.x); a[1]  += c * bfhi(u0.x);
        a[2]  += c * bflo(u0.y); a[3]  += c * bfhi(u0.y);
        a[4]  += c * bflo(u0.z); a[5]  += c * bfhi(u0.z);
        a[6]  += c * bflo(u0.w); a[7]  += c * bfhi(u0.w);
        a[8]  += c * bflo(u1.x); a[9]  += c * bfhi(u1.x);
        a[10] += c * bflo(u1.y); a[11] += c * bfhi(u1.y);
        a[12] += c * bflo(u1.z); a[13] += c * bfhi(u1.z);
        a[14] += c * bflo(u1.w); a[15] += c * bfhi(u1.w);
    }
#pragma unroll 4
    for (int d = 0; d < np1; d++) {
        int   q = 8 * d + g;
        int   r = __shfl(r1v, q, 32);
        float c = __shfl(d1v, q, 32);
        uint4 u0 = Aq[r * 8 + f];
        uint4 u1 = Aq[r * 8 + 4 + f];
        a[0]  += c * bflo(u0.x); a[1]  += c * bfhi(u0.x);
        a[2]  += c * bflo(u0.y); a[3]  += c * bfhi(u0.y);
        a[4]  += c * bflo(u0.z); a[5]  += c * bfhi(u0.z);
        a[6]  += c * bflo(u0.w); a[7]  += c * bfhi(u0.w);
        a[8]  += c * bflo(u1.x); a[9]  += c * bfhi(u1.x);
        a[10] += c * bflo(u1.y); a[11] += c * bfhi(u1.y);
        a[12] += c * bflo(u1.z); a[13] += c * bfhi(u1.z);
        a[14] += c * bflo(u1.w); a[15] += c * bfhi(u1.w);
    }
    if (deg > CAP) {                         // CAP overflow (normally none)
        int m = ovf_cnt[0];
        for (int k2 = 0; k2 < m; k2++) {
            unsigned p = ovf[k2];
            if ((int)(p & 0xffffu) == n && g == 0) {
                int r = (int)(p >> 16);
                float c = rsqrtf(1.0f + (float)cnt[r]);
                uint4 u0 = Aq[r * 8 + f], u1 = Aq[r * 8 + 4 + f];
                a[0]  += c * bflo(u0.x); a[1]  += c * bfhi(u0.x);
                a[2]  += c * bflo(u0.y); a[3]  += c * bfhi(u0.y);
                a[4]  += c * bflo(u0.z); a[5]  += c * bfhi(u0.z);
                a[6]  += c * bflo(u0.w); a[7]  += c * bfhi(u0.w);
                a[8]  += c * bflo(u1.x); a[9]  += c * bfhi(u1.x);
                a[10] += c * bflo(u1.y); a[11] += c * bfhi(u1.y);
                a[12] += c * bflo(u1.z); a[13] += c * bfhi(u1.z);
                a[14] += c * bflo(u1.w); a[15] += c * bfhi(u1.w);
            }
        }
    }
#pragma unroll
    for (int k = 0; k < 16; k++) {
        a[k] += __shfl_xor(a[k], 4, 32);
        a[k] += __shfl_xor(a[k], 8, 32);
        a[k] += __shfl_xor(a[k], 16, 32);
    }

    float di = rsqrtf(1.0f + (float)deg);
    float dd = di * di;
    uint4 s0 = Aq[n * 8 + f], s1 = Aq[n * 8 + 4 + f];
    float4 bA0 = ((const float4*)bias)[2 * f];
    float4 bA1 = ((const float4*)bias)[2 * f + 1];
    float4 bB0 = ((const float4*)(bias + 32))[2 * f];
    float4 bB1 = ((const float4*)(bias + 32))[2 * f + 1];
    if (g == 0) {
        float* dst = sB + nl * 64 + 8 * f;
        dst[0] = fmaxf(di * a[0]  + dd * bflo(s0.x) + bA0.x, 0.f);
        dst[1] = fmaxf(di * a[1]  + dd * bfhi(s0.x) + bA0.y, 0.f);
        dst[2] = fmaxf(di * a[2]  + dd * bflo(s0.y) + bA0.z, 0.f);
        dst[3] = fmaxf(di * a[3]  + dd * bfhi(s0.y) + bA0.w, 0.f);
        dst[4] = fmaxf(di * a[4]  + dd * bflo(s0.z) + bA1.x, 0.f);
        dst[5] = fmaxf(di * a[5]  + dd * bfhi(s0.z) + bA1.y, 0.f);
        dst[6] = fmaxf(di * a[6]  + dd * bflo(s0.w) + bA1.z, 0.f);
        dst[7] = fmaxf(di * a[7]  + dd * bfhi(s0.w) + bA1.w, 0.f);
        float* dst2 = dst + 32;
        dst2[0] = fmaxf(di * a[8]  + dd * bflo(s1.x) + bB0.x, 0.f);
        dst2[1] = fmaxf(di * a[9]  + dd * bfhi(s1.x) + bB0.y, 0.f);
        dst2[2] = fmaxf(di * a[10] + dd * bflo(s1.y) + bB0.z, 0.f);
        dst2[3] = fmaxf(di * a[11] + dd * bfhi(s1.y) + bB0.w, 0.f);
        dst2[4] = fmaxf(di * a[12] + dd * bflo(s1.z) + bB1.x, 0.f);
        dst2[5] = fmaxf(di * a[13] + dd * bfhi(s1.z) + bB1.y, 0.f);
        dst2[6] = fmaxf(di * a[14] + dd * bflo(s1.w) + bB1.z, 0.f);
        dst2[7] = fmaxf(di * a[15] + dd * bfhi(s1.w) + bB1.w, 0.f);
    }
    __syncthreads();

    // ---- GEMM: C[32x64] = sB[32x64] @ sW[64x64], 2 rows/thread ----------
    int col = tid & 63;
    int r0  = tid >> 6;           // 0..15; rows r0 and r0+16
    float acc0 = 0.f, acc1 = 0.f;
#pragma unroll
    for (int kk = 0; kk < 64; kk++) {
        float wv = sW[kk * 64 + col];
        acc0 += sB[r0 * 64 + kk] * wv;
        acc1 += sB[(r0 + 16) * 64 + kk] * wv;
    }
    int na = blockIdx.x * 32 + r0;
    C[na * 64 + col]        = f2bf(acc0);
    C[(na + 16) * 64 + col] = f2bf(acc1);
}

// ---- layer-2 pull aggregation (normalize epilogue), merged rows ----------
__global__ void k_aggf4(const uint4* __restrict__ Cq, uint4* __restrict__ Hq,
                        const int* __restrict__ cnt,
                        const unsigned short* __restrict__ ebuf, const float* __restrict__ bias,
                        const unsigned* __restrict__ ovf, const int* __restrict__ ovf_cnt) {
    int w = (blockIdx.x * 256 + threadIdx.x) >> 6;   // wave id, 2 nodes/wave
    int lane = threadIdx.x & 63;
    int half = lane >> 5, sl = lane & 31;
    int n = w * 2 + half;
    if (n >= N_NODES) return;
    int deg = cnt[n];
    int bucketed = min(deg, CAP);
    int nb0 = min(bucketed, 32);
    int nb1 = bucketed - nb0;

    int   r0v = 0, r1v = 0;
    float d0v = 0.0f, d1v = 0.0f;
    if (sl < nb0) { r0v = (int)ebuf[n * CAP + sl];      d0v = rsqrtf(1.0f + (float)cnt[r0v]); }
    if (sl < nb1) { r1v = (int)ebuf[n * CAP + 32 + sl]; d1v = rsqrtf(1.0f + (float)cnt[r1v]); }

    int g = sl >> 2;
    int f = sl & 3;

    float a[16];
#pragma unroll
    for (int k = 0; k < 16; k++) a[k] = 0.f;
    int np0 = (nb0 + 7) >> 3;
    int np1 = (nb1 + 7) >> 3;

#pragma unroll 4
    for (int d = 0; d < np0; d++) {
        int   q = 8 * d + g;
        int   r = __shfl(r0v, q, 32);
        float c = __shfl(d0v, q, 32);
        uint4 u0 = Cq[r * 8 + f];
        uint4 u1 = Cq[r * 8 + 4 + f];
        a[0]  += c * bflo(u0.x); a[1]  += c * bfhi(u0.x);
        a[2]  += c * bflo(u0.y); a[3]  += c * bfhi(u0.y);
        a[4]  += c * bflo(u0.z); a[5]  += c * bfhi(u0.z);
        a[6]  += c * bflo(u0.w); a[7]  += c * bfhi(u0.w);
        a[8]  += c * bflo(u1.x); a[9]  += c * bfhi(u1.x);
        a[10] += c * bflo(u1.y); a[11] += c * bfhi(u1.y);
        a[12] += c * bflo(u1.z); a[13] += c * bfhi(u1.z);
        a[14] += c * bflo(u1.w); a[15] += c * bfhi(u1.w);
    }
#pragma unroll 4
    for (int d = 0; d < np1; d++) {
        int   q = 8 * d + g;
        int   r = __shfl(r1v, q, 32);
        float c = __shfl(d1v, q, 32);
        uint4 u0 = Cq[r * 8 + f];
        uint4 u1 = Cq[r * 8 + 4 + f];
        a[0]  += c * bflo(u0.x); a[1]  += c * bfhi(u0.x);
        a[2]  += c * bflo(u0.y); a[3]  += c * bfhi(u0.y);
        a[4]  += c * bflo(u0.z); a[5]  += c * bfhi(u0.z);
        a[6]  += c * bflo(u0.w); a[7]  += c * bfhi(u0.w);
        a[8]  += c * bflo(u1.x); a[9]  += c * bfhi(u1.x);
        a[10] += c * bflo(u1.y); a[11] += c * bfhi(u1.y);
        a[12] += c * bflo(u1.z); a[13] += c * bfhi(u1.z);
        a[14] += c * bflo(u1.w); a[15] += c * bfhi(u1.w);
    }
    if (deg > CAP) {
        int m = ovf_cnt[0];
        for (int k2 = 0; k2 < m; k2++) {
            unsigned p = ovf[k2];
            if ((int)(p & 0xffffu) == n && g == 0) {
                int r = (int)(p >> 16);
                float c = rsqrtf(1.0f + (float)cnt[r]);
                uint4 u0 = Cq[r * 8 + f], u1 = Cq[r * 8 + 4 + f];
                a[0]  += c * bflo(u0.x); a[1]  += c * bfhi(u0.x);
                a[2]  += c * bflo(u0.y); a[3]  += c * bfhi(u0.y);
                a[4]  += c * bflo(u0.z); a[5]  += c * bfhi(u0.z);
                a[6]  += c * bflo(u0.w); a[7]  += c * bfhi(u0.w);
                a[8]  += c * bflo(u1.x); a[9]  += c * bfhi(u1.x);
                a[10] += c * bflo(u1.y); a[11] += c * bfhi(u1.y);
                a[12] += c * bflo(u1.z); a[13] += c * bfhi(u1.z);
                a[14] += c * bflo(u1.w); a[15] += c * bfhi(u1.w);
            }
        }
    }
#pragma unroll
    for (int k = 0; k < 16; k++) {
        a[k] += __shfl_xor(a[k], 4, 32);
        a[k] += __shfl_xor(a[k], 8, 32);
        a[k] += __shfl_xor(a[k], 16, 32);
    }

    float di = rsqrtf(1.0f + (float)deg);
    float dd = di * di;
    uint4 s0 = Cq[n * 8 + f], s1 = Cq[n * 8 + 4 + f];
    float4 bA0 = ((const float4*)bias)[2 * f];
    float4 bA1 = ((const float4*)bias)[2 * f + 1];
    float4 bB0 = ((const float4*)(bias + 32))[2 * f];
    float4 bB1 = ((const float4*)(bias + 32))[2 * f + 1];
    float v[16];
    v[0]  = di * a[0]  + dd * bflo(s0.x) + bA0.x;
    v[1]  = di * a[1]  + dd * bfhi(s0.x) + bA0.y;
    v[2]  = di * a[2]  + dd * bflo(s0.y) + bA0.z;
    v[3]  = di * a[3]  + dd * bfhi(s0.y) + bA0.w;
    v[4]  = di * a[4]  + dd * bflo(s0.z) + bA1.x;
    v[5]  = di * a[5]  + dd * bfhi(s0.z) + bA1.y;
    v[6]  = di * a[6]  + dd * bflo(s0.w) + bA1.z;
    v[7]  = di * a[7]  + dd * bfhi(s0.w) + bA1.w;
    v[8]  = di * a[8]  + dd * bflo(s1.x) + bB0.x;
    v[9]  = di * a[9]  + dd * bfhi(s1.x) + bB0.y;
    v[10] = di * a[10] + dd * bflo(s1.y) + bB0.z;
    v[11] = di * a[11] + dd * bfhi(s1.y) + bB0.w;
    v[12] = di * a[12] + dd * bflo(s1.z) + bB1.x;
    v[13] = di * a[13] + dd * bfhi(s1.z) + bB1.y;
    v[14] = di * a[14] + dd * bflo(s1.w) + bB1.z;
    v[15] = di * a[15] + dd * bfhi(s1.w) + bB1.w;

    float s = 0.f;
#pragma unroll
    for (int k = 0; k < 16; k++) s += v[k] * v[k];
    s += __shfl_xor(s, 1, 32);
    s += __shfl_xor(s, 2, 32);
    float inv = 1.0f / fmaxf(sqrtf(s), 1e-12f);
#pragma unroll
    for (int k = 0; k < 16; k++) v[k] *= inv;
    if (g == 0) {
        Hq[n * 8 + f]     = make_uint4(pack2(v[0], v[1]),  pack2(v[2], v[3]),
                                       pack2(v[4], v[5]),  pack2(v[6], v[7]));
        Hq[n * 8 + 4 + f] = make_uint4(pack2(v[8], v[9]),  pack2(v[10], v[11]),
                                       pack2(v[12], v[13]), pack2(v[14], v[15]));
    }
}

// ---- fused edge dot + finalize + symmetrize: 2 lanes/edge ----------------
// Lane f in {0,1} loads 64 B (4 consecutive uint4) of i's row and of j's row
// -> 8 outstanding loads/lane, lane pairs cover each 128 B row contiguously.
__global__ void k_dotsym(const uint4* __restrict__ Hq,
                         const float* __restrict__ s_d, const int* __restrict__ j_idx,
                         const unsigned char* __restrict__ revb,
                         float* __restrict__ outS) {   // d_out + 2E, holds vals_s [2E]
    int t = blockIdx.x * 256 + threadIdx.x;   // NE*2 threads
    int e = t >> 1;
    int f = t & 1;
    int i = e / KNN;
    int j = j_idx[e];
    const uint4* Hi = Hq + i * 8 + 4 * f;
    const uint4* Hj = Hq + j * 8 + 4 * f;
    uint4 a0 = Hi[0], a1 = Hi[1], a2 = Hi[2], a3 = Hi[3];
    uint4 b0 = Hj[0], b1 = Hj[1], b2 = Hj[2], b3 = Hj[3];
    float s = dot8(a0, b0) + dot8(a1, b1) + dot8(a2, b2) + dot8(a3, b3);
    s += __shfl_xor(s, 1);
    if (f == 0) {
        float base = OMEGA * fmaxf(s, 0.0f);
        int rt = revb[e];
        float vv, v2;
        if (rt != 255) {                     // reverse edge exists (rare)
            int rev = j * KNN + rt;
            vv = base + 0.5f * (1.0f - OMEGA) * (s_d[e] + s_d[rev]);
            v2 = 0.0f;
        } else {
            vv = base + (1.0f - OMEGA) * s_d[e];
            v2 = vv;
        }
        outS[e] = vv;
        outS[NE + e] = v2;
    }
}

// ---- binned in-edge accumulation + fused dinv2 ---------------------------
__global__ void k_jagg(const unsigned* __restrict__ jbbuf, const int* __restrict__ jbcnt,
                       const float* __restrict__ outS, float* __restrict__ dinv2,
                       const unsigned* __restrict__ jovf, const int* __restrict__ jovf_cnt,
                       const int* __restrict__ j_idx) {
    __shared__ float ld[512];
    int b = blockIdx.x;
    int tid = threadIdx.x;                   // 1024 threads
    if (tid < 512) ld[tid] = 0.0f;
    __syncthreads();
    const float* outSv2 = outS + NE;
    int n = min(jbcnt[b], JBCAP);
    for (int idx = tid; idx < n; idx += 1024) {
        unsigned p = jbbuf[b * JBCAP + idx];
        atomicAdd(&ld[p >> 20], outSv2[p & 0xFFFFFu]);
    }
    int m = jovf_cnt[0];                     // learner bin overflow (normally 0)
    for (int t2 = tid; t2 < m; t2 += 1024) {
        int e = (int)(jovf[t2] & 0xFFFFFu);
        int j = j_idx[e];
        if ((j >> 9) == b) atomicAdd(&ld[j & 511], outSv2[e]);
    }
    __syncthreads();
    if (tid < 512) {
        int node = b * 512 + tid;
        if (node < N_NODES) {
            float d = ld[tid];
            const float* pp = outS + node * KNN;
#pragma unroll
            for (int qq = 0; qq < KNN; qq++) d += pp[qq];
            dinv2[node] = (d > 0.0f) ? rsqrtf(fmaxf(d, 1e-12f)) : 0.0f;
        }
    }
}

// ---- final normalization: vals_norm = dinv2[r] * vals_s * dinv2[c] -------
__global__ void k_norm(const float* __restrict__ outS, const float* __restrict__ dinv2,
                       const int* __restrict__ j_idx, float* __restrict__ out) {
    int t = blockIdx.x * 256 + threadIdx.x;   // 2*NE threads
    int r, c;
    if (t < NE) { r = t / KNN; c = j_idx[t]; }
    else        { int e = t - NE; r = j_idx[e]; c = e / KNN; }
    out[t] = dinv2[r] * outS[t] * dinv2[c];
}

extern "C" void kernel_launch(void* const* d_in, const int* in_sizes, int n_in,
                              void* d_out, int out_size, void* d_ws, size_t ws_size,
                              hipStream_t stream) {
    const float* features = (const float*)d_in[0];
    const float* W1       = (const float*)d_in[1];
    const float* b1       = (const float*)d_in[2];
    const float* W2       = (const float*)d_in[3];
    const float* b2       = (const float*)d_in[4];
    const float* s_d      = (const float*)d_in[5];
    const int*   adj_row  = (const int*)d_in[6];
    const int*   adj_col  = (const int*)d_in[7];
    const int*   j_idx    = (const int*)d_in[9];
    float* out = (float*)d_out;

    const int N64 = N_NODES * 64;
    // Workspace layout (zero region first, all offsets 16B-aligned):
    // [cnt N][ovfcnts 16][bcnt 80][jbcnt 80]  <- memset 0
    // [dinv2 N][A N64 us][C N64 us][H N64 us]
    // [ebuf N*CAP us][ovf NE u][revb NE uc][bbuf][jbbuf][ovf2 NE u][jovf NE u]
    int*   cnt     = (int*)d_ws;
    int*   ovfcnts = cnt + N_NODES;          // [0]=CAP ovf, [4]=adj bin ovf, [8]=learner bin ovf
    int*   bcnt    = ovfcnts + 16;
    int*   jbcnt   = bcnt + NBUCK;
    float* dinv2   = (float*)(jbcnt + NBUCK);
    unsigned short* A   = (unsigned short*)(dinv2 + N_NODES);
    unsigned short* C   = A + N64;
    unsigned short* H   = C + N64;
    unsigned short* ebuf = H + N64;              // N*CAP ushorts
    unsigned* ovf    = (unsigned*)(ebuf + N_NODES * CAP);
    unsigned char* revb = (unsigned char*)(ovf + NE);
    unsigned* bbuf   = (unsigned*)(revb + NE);   // NBUCK*BCAP
    unsigned* jbbuf  = bbuf + NBUCK * BCAP;      // NBUCK*JBCAP
    unsigned* ovf2   = jbbuf + NBUCK * JBCAP;    // NE
    unsigned* jovf   = ovf2 + NE;                // NE

    // Re-init (ws is poisoned 0xAA before every call)
    size_t zero_bytes = (size_t)(N_NODES + 16 + 2 * NBUCK) * 4;
    hipMemsetAsync(cnt, 0, zero_bytes, stream);

    // Mega front end: gemm1 + bin(both sets) + reverse-edge scan (1 thr/edge)
    const int GB = N_NODES / 32;                          // 1250
    const int NBA = (NE + 256 * EPT - 1) / (256 * EPT);   // 469
    const int RB = NE / 256;                              // 3750
    k_mega1<<<GB + 2 * NBA + RB, 256, 0, stream>>>(
        features, W1, A, adj_row, adj_col, j_idx,
        bcnt, bbuf, ovf2, ovfcnts + 4, jbcnt, jbbuf, jovf, ovfcnts + 8, revb);

    // Per-bucket scatter (LDS slots, no global atomics) -> ebuf + cnt
    k_scatter3<<<NBUCK, 1024, 0, stream>>>(bbuf, bcnt, cnt, ebuf,
                                           ovf, ovfcnts, ovf2, ovfcnts + 4);

    // Fused layer-1: agg(A)+ReLU -> LDS -> xW2 -> C
    k_aggemm1<<<N_NODES / 32, 1024, 0, stream>>>(
        (const uint4*)A, W2, C, cnt, ebuf, b1, ovf, ovfcnts);

    // Layer-2 aggregate + normalize -> H
    k_aggf4<<<(N_NODES / 2 * 64 + 255) / 256, 256, 0, stream>>>(
        (const uint4*)C, (uint4*)H, cnt, ebuf, b2, ovf, ovfcnts);

    // Fused edge scores + symmetrize (atomic-free, 2 lanes/edge, 8 loads/lane)
    float* outS = out + 2 * NE;
    k_dotsym<<<NE * 2 / 256, 256, 0, stream>>>(
        (const uint4*)H, s_d, j_idx, revb, outS);

    // Binned in-edge accumulation + dinv2, then final normalize
    k_jagg<<<NBUCK, 1024, 0, stream>>>(jbbuf, jbcnt, outS, dinv2, jovf, ovfcnts + 8, j_idx);
    k_norm<<<2 * NE / 256, 256, 0, stream>>>(outS, dinv2, j_idx, out);
}